// Round 1
// baseline (6072.514 us; speedup 1.0000x reference)
//
#include <hip/hip_runtime.h>
#include <math.h>

#define S_ 512
#define B_ 128
#define D_ 512
#define I_ 64
#define F_ 2048
#define H_ 8
#define DK_ 64
#define L_ 4
#define SB_ (S_*B_)

typedef unsigned short u16;
typedef unsigned int u32;
typedef __attribute__((ext_vector_type(4))) unsigned int u32x4;
typedef __attribute__((ext_vector_type(4))) float f32x4;

__device__ __forceinline__ u16 f2bf(float f){
  u32 x = __builtin_bit_cast(u32, f);
  x += 0x7fffu + ((x >> 16) & 1u);
  return (u16)(x >> 16);
}

__device__ __forceinline__ void mfma16(f32x4& c, const u32x4& a, const u32x4& b){
  asm volatile("v_mfma_f32_16x16x32_bf16 %0, %1, %2, %0" : "+v"(c) : "v"(a), "v"(b));
}

// ---------------- positional encoding table ----------------
__global__ void pe_kernel(float* __restrict__ pe){
  int s = blockIdx.x, d = threadIdx.x;
  float e = expf((float)(d & ~1) * (-9.210340371976184f / (float)D_)); // -ln(10000)/D * 2k
  float arg = (float)s * e;
  pe[s*D_ + d] = (d & 1) ? cosf(arg) : sinf(arg);
}

// ---------------- weight transpose + fp32->bf16 ----------------
// src: nmat x R x C (row major). dst: nmat x C x R bf16 (dst[z][c][r] = src[z][r][c])
__global__ void transpose_bf16(const float* __restrict__ src, u16* __restrict__ dst,
                               int R, int C){
  __shared__ float t[32][33];
  size_t base = (size_t)blockIdx.z * R * C;
  int r0 = blockIdx.y*32, c0 = blockIdx.x*32;
  int tx = threadIdx.x, ty = threadIdx.y;
  #pragma unroll
  for (int j=0;j<4;j++)
    t[ty+j*8][tx] = src[base + (size_t)(r0+ty+j*8)*C + c0+tx];
  __syncthreads();
  #pragma unroll
  for (int j=0;j<4;j++)
    dst[base + (size_t)(c0+ty+j*8)*R + r0+tx] = f2bf(t[tx][ty+j*8]);
}

// ---------------- input projection + scale + PE ----------------
// h[s*B+b][d] = (x[b][s][:] @ Win + bin)*sqrt(D) + pe[s][d]
__global__ __launch_bounds__(512) void inproj_kernel(const float* __restrict__ x,
    const float* __restrict__ Win, const float* __restrict__ bin,
    const float* __restrict__ pe, float* __restrict__ h){
  int r = blockIdx.x;
  int s = r >> 7, b = r & (B_-1);
  int d = threadIdx.x;
  __shared__ float xs[I_];
  if (d < I_) xs[d] = x[((size_t)b*S_ + s)*I_ + d];
  __syncthreads();
  float acc = 0.f;
  #pragma unroll 16
  for (int i=0;i<I_;i++) acc = fmaf(xs[i], Win[i*D_ + d], acc);
  h[(size_t)r*D_ + d] = (acc + bin[d]) * 22.627416997969522f + pe[s*D_ + d];
}

// ---------------- LayerNorm ----------------
// FINAL==0: outb (bf16) same (S*B, D) layout.  FINAL==1: outf fp32, (B,S,D) permuted.
template<int FINAL>
__global__ __launch_bounds__(256) void ln_kernel(const float* __restrict__ hsrc,
    const float* __restrict__ g, const float* __restrict__ bb,
    u16* __restrict__ outb, float* __restrict__ outf){
  int row = blockIdx.x*4 + (threadIdx.x>>6);
  int lane = threadIdx.x & 63;
  const float* hr = hsrc + (size_t)row*D_ + lane*8;
  f32x4 a0 = *(const f32x4*)hr;
  f32x4 a1 = *(const f32x4*)(hr+4);
  float v[8];
  #pragma unroll
  for (int j=0;j<4;j++){ v[j]=a0[j]; v[4+j]=a1[j]; }
  float sum = 0.f;
  #pragma unroll
  for (int j=0;j<8;j++) sum += v[j];
  #pragma unroll
  for (int m=1;m<64;m<<=1) sum += __shfl_xor(sum, m);
  float mean = sum * (1.f/(float)D_);
  float s2 = 0.f;
  #pragma unroll
  for (int j=0;j<8;j++){ float dd = v[j]-mean; s2 = fmaf(dd,dd,s2); }
  #pragma unroll
  for (int m=1;m<64;m<<=1) s2 += __shfl_xor(s2, m);
  float inv = rsqrtf(s2*(1.f/(float)D_) + 1e-5f);
  f32x4 g0 = *(const f32x4*)&g[lane*8];
  f32x4 g1 = *(const f32x4*)&g[lane*8+4];
  f32x4 b0 = *(const f32x4*)&bb[lane*8];
  f32x4 b1 = *(const f32x4*)&bb[lane*8+4];
  float o[8];
  #pragma unroll
  for (int j=0;j<4;j++){
    o[j]   = (v[j]-mean)*inv*g0[j] + b0[j];
    o[4+j] = (v[4+j]-mean)*inv*g1[j] + b1[j];
  }
  if (FINAL == 0){
    u32x4 pk;
    #pragma unroll
    for (int j=0;j<4;j++)
      pk[j] = (u32)f2bf(o[2*j]) | ((u32)f2bf(o[2*j+1])<<16);
    *(u32x4*)&outb[(size_t)row*D_ + lane*8] = pk;
  } else {
    int s = row>>7, b = row&(B_-1);
    float* op = outf + ((size_t)b*S_ + s)*D_ + lane*8;
    f32x4 r0, r1;
    #pragma unroll
    for (int j=0;j<4;j++){ r0[j]=o[j]; r1[j]=o[4+j]; }
    *(f32x4*)op = r0;
    *(f32x4*)(op+4) = r1;
  }
}

// ---------------- bf16 MFMA GEMM, 128x128 tile, 4 waves ----------------
// A: (65536, K) bf16 row-major.  Wt: (N, K) bf16 row-major (transposed weights).
// MODE 0: QKV -> outb[((s*H+hh)*B+b)*64+dd]  (s=r>>7,b=r&127,hh=n>>6,dd=n&63)
// MODE 1: hres[r*512+n] += dot + bias[n]
// MODE 2: outb[r*N+n] = bf16(gelu_exact(dot + bias[n]))
template<int MODE>
__global__ __launch_bounds__(256) void gemm_kernel(const u16* __restrict__ A,
    const u16* __restrict__ Wt, const float* __restrict__ bias,
    float* __restrict__ hres, u16* __restrict__ outb, int N, int K){
  const int m0 = blockIdx.x*128, n0 = blockIdx.y*128;
  __shared__ u16 a_lds[128*40];
  __shared__ u16 b_lds[128*40];
  const int t = threadIdx.x;
  const int lane = t & 63, wave = t >> 6;
  const int wm = wave >> 1, wn = wave & 1;
  const int rsel = lane & 15, kg = (lane>>4)*8;
  f32x4 acc[4][4] = {};
  for (int k0 = 0; k0 < K; k0 += 32){
    asm volatile("s_nop 7\n\ts_nop 7"); // WAR insurance: prev MFMAs vs new reg writes
    __syncthreads();
    #pragma unroll
    for (int rr=0; rr<2; rr++){
      int idx = rr*2048 + t*8;
      int row = idx >> 5, col = idx & 31;
      *(u32x4*)&a_lds[row*40+col] = *(const u32x4*)&A[(size_t)(m0+row)*K + k0 + col];
      *(u32x4*)&b_lds[row*40+col] = *(const u32x4*)&Wt[(size_t)(n0+row)*K + k0 + col];
    }
    __syncthreads();
    u32x4 af[4], bfr[4];
    #pragma unroll
    for (int i=0;i<4;i++){
      af[i]  = *(const u32x4*)&a_lds[(wm*64 + i*16 + rsel)*40 + kg];
      bfr[i] = *(const u32x4*)&b_lds[(wn*64 + i*16 + rsel)*40 + kg];
    }
    #pragma unroll
    for (int i=0;i<4;i++)
      #pragma unroll
      for (int j=0;j<4;j++)
        mfma16(acc[i][j], af[i], bfr[j]);
  }
  asm volatile("s_nop 7\n\ts_nop 7");
  const int rb = (lane>>4)*4;
  #pragma unroll
  for (int i=0;i<4;i++){
    #pragma unroll
    for (int j=0;j<4;j++){
      int gn = n0 + wn*64 + j*16 + rsel;
      #pragma unroll
      for (int rg=0;rg<4;rg++){
        int gr = m0 + wm*64 + i*16 + rb + rg;
        float val = acc[i][j][rg];
        if (MODE == 0){
          int s = gr >> 7, b = gr & 127, hh = gn >> 6, dd = gn & 63;
          outb[(size_t)((s*H_ + hh)*B_ + b)*DK_ + dd] = f2bf(val);
        } else if (MODE == 1){
          hres[(size_t)gr*D_ + gn] += val + bias[gn];
        } else {
          float xg = val + bias[gn];
          float ge = 0.5f*xg*(1.f + erff(xg*0.7071067811865476f));
          outb[(size_t)gr*(size_t)N + gn] = f2bf(ge);
        }
      }
    }
  }
}

// ---------------- fused batch-attention per (s, head) ----------------
// q,k,v: (S*H, B, DK) bf16. cb: (S*B, D) bf16 ctx output.
__global__ __launch_bounds__(256) void attn_kernel(const u16* __restrict__ qb,
    const u16* __restrict__ kb, const u16* __restrict__ vb, u16* __restrict__ cb){
  __shared__ __align__(16) char smem[118784];
  u16* q_lds = (u16*)smem;                 // [128][72]
  u16* k_lds = (u16*)(smem + 18432);       // [128][72]
  float* s_lds = (float*)smem;             // [128][129]  (overlays q,k after QK^T)
  u16* p_lds = (u16*)(smem + 66048);       // [128][136]
  u16* vT    = (u16*)(smem + 100864);      // [64][136]
  float* rsum = (float*)(smem + 118272);   // [128]
  int sh = blockIdx.x;
  int s = sh >> 3, hh = sh & 7;
  int t = threadIdx.x, lane = t & 63, wave = t >> 6;
  const u16* qg = qb + (size_t)sh * (B_*DK_);
  const u16* kg = kb + (size_t)sh * (B_*DK_);
  const u16* vg = vb + (size_t)sh * (B_*DK_);
  #pragma unroll
  for (int rr=0; rr<4; rr++){
    int idx = rr*2048 + t*8;
    int row = idx >> 6, col = idx & 63;
    *(u32x4*)&q_lds[row*72+col] = *(const u32x4*)&qg[idx];
    *(u32x4*)&k_lds[row*72+col] = *(const u32x4*)&kg[idx];
  }
  #pragma unroll
  for (int rr=0; rr<16; rr++){
    int idx2 = (rr*256 + t)*2;
    u32 u = *(const u32*)&vg[idx2];
    int c = idx2 >> 6, d0 = idx2 & 63;
    vT[d0*136 + c]     = (u16)(u & 0xffffu);
    vT[(d0+1)*136 + c] = (u16)(u >> 16);
  }
  __syncthreads();
  int wm = wave>>1, wn = wave&1;
  int rsel = lane & 15;
  f32x4 sacc[4][4] = {};
  #pragma unroll
  for (int ks=0; ks<2; ks++){
    asm volatile("s_nop 7\n\ts_nop 7");
    int ko = ks*32 + (lane>>4)*8;
    u32x4 qf[4], kf[4];
    #pragma unroll
    for (int i=0;i<4;i++){
      qf[i] = *(const u32x4*)&q_lds[(wm*64+i*16+rsel)*72 + ko];
      kf[i] = *(const u32x4*)&k_lds[(wn*64+i*16+rsel)*72 + ko];
    }
    #pragma unroll
    for (int i=0;i<4;i++)
      #pragma unroll
      for (int j=0;j<4;j++)
        mfma16(sacc[i][j], qf[i], kf[j]);
  }
  asm volatile("s_nop 7\n\ts_nop 7");
  __syncthreads();  // all waves done reading q,k
  int rb = (lane>>4)*4;
  #pragma unroll
  for (int i=0;i<4;i++)
    #pragma unroll
    for (int j=0;j<4;j++)
      #pragma unroll
      for (int rg=0;rg<4;rg++)
        s_lds[(wm*64+i*16+rb+rg)*129 + wn*64+j*16+rsel] = sacc[i][j][rg] * 0.125f;
  __syncthreads();
  if (t < B_){
    float kv[12];
    #pragma unroll
    for (int i=0;i<12;i++) kv[i] = -3.4e38f;
    const float* srow = &s_lds[t*129];
    for (int i=0;i<B_;i++){
      float v = srow[i];
      if (v > kv[11]){
        float inc = v;
        #pragma unroll
        for (int p=0;p<12;p++){      // bubble insert, static indices only
          float cur = kv[p];
          bool gt = inc > cur;
          kv[p] = gt ? inc : cur;
          inc   = gt ? cur : inc;
        }
      }
    }
    float kth = kv[11], mx = kv[0];
    float sum = 0.f;
    u16* prow = &p_lds[t*136];
    for (int i=0;i<B_;i++){
      float v = srow[i];
      float e = (v >= kth) ? expf(v - mx) : 0.f;
      sum += e;
      prow[i] = f2bf(e);
    }
    rsum[t] = sum;
  }
  __syncthreads();
  f32x4 cacc[4][2] = {};
  #pragma unroll
  for (int ks=0; ks<4; ks++){
    asm volatile("s_nop 7\n\ts_nop 7");
    int ko = ks*32 + (lane>>4)*8;
    u32x4 pf[4], vf[2];
    #pragma unroll
    for (int i=0;i<4;i++) pf[i] = *(const u32x4*)&p_lds[(wm*64+i*16+rsel)*136 + ko];
    #pragma unroll
    for (int j=0;j<2;j++) vf[j] = *(const u32x4*)&vT[(wn*32+j*16+rsel)*136 + ko];
    #pragma unroll
    for (int i=0;i<4;i++)
      #pragma unroll
      for (int j=0;j<2;j++)
        mfma16(cacc[i][j], pf[i], vf[j]);
  }
  asm volatile("s_nop 7\n\ts_nop 7");
  #pragma unroll
  for (int i=0;i<4;i++)
    #pragma unroll
    for (int j=0;j<2;j++)
      #pragma unroll
      for (int rg=0;rg<4;rg++){
        int m = wm*64 + i*16 + rb + rg;
        int n = wn*32 + j*16 + rsel;
        float val = cacc[i][j][rg] * (1.f / rsum[m]);
        cb[((size_t)(s*B_ + m))*D_ + hh*DK_ + n] = f2bf(val);
      }
}

extern "C" void kernel_launch(void* const* d_in, const int* in_sizes, int n_in,
                              void* d_out, int out_size, void* d_ws, size_t ws_size,
                              hipStream_t stream) {
  const float* x    = (const float*)d_in[0];
  const float* Win  = (const float*)d_in[1];
  const float* bin  = (const float*)d_in[2];
  const float* ln1g = (const float*)d_in[3];
  const float* ln1b = (const float*)d_in[4];
  const float* Wq   = (const float*)d_in[5];
  const float* Wk   = (const float*)d_in[6];
  const float* Wv   = (const float*)d_in[7];
  const float* Wo   = (const float*)d_in[8];
  const float* bo   = (const float*)d_in[9];
  const float* ln2g = (const float*)d_in[10];
  const float* ln2b = (const float*)d_in[11];
  const float* W1   = (const float*)d_in[12];
  const float* b1   = (const float*)d_in[13];
  const float* W2   = (const float*)d_in[14];
  const float* b2   = (const float*)d_in[15];
  const float* lnfg = (const float*)d_in[16];
  const float* lnfb = (const float*)d_in[17];

  char* ws = (char*)d_ws;
  float* h  = (float*)(ws);                      // 134217728 B
  u16* yb   = (u16*)(ws + 134217728ull);         // 67108864 B
  u16* qb   = (u16*)(ws + 201326592ull);         // 67108864 B
  u16* kb   = (u16*)(ws + 268435456ull);
  u16* vb   = (u16*)(ws + 335544320ull);
  u16* cb   = (u16*)(ws + 402653184ull);
  u16* act  = qb;                                // overlays qb..cb (268435456 B)
  u16* wqT  = (u16*)(ws + 469762048ull);         // L*D*D each = 2 MB
  u16* wkT  = wqT + (size_t)L_*D_*D_;
  u16* wvT  = wkT + (size_t)L_*D_*D_;
  u16* woT  = wvT + (size_t)L_*D_*D_;
  u16* w1T  = (u16*)(ws + 478150656ull);         // L*D*F = 8 MB
  u16* w2T  = (u16*)(ws + 486539264ull);         // 8 MB
  float* pe = (float*)(ws + 494927872ull);       // 1 MB

  dim3 tb(32,8);
  pe_kernel<<<S_, D_, 0, stream>>>(pe);
  transpose_bf16<<<dim3(D_/32, D_/32, L_), tb, 0, stream>>>(Wq, wqT, D_, D_);
  transpose_bf16<<<dim3(D_/32, D_/32, L_), tb, 0, stream>>>(Wk, wkT, D_, D_);
  transpose_bf16<<<dim3(D_/32, D_/32, L_), tb, 0, stream>>>(Wv, wvT, D_, D_);
  transpose_bf16<<<dim3(D_/32, D_/32, L_), tb, 0, stream>>>(Wo, woT, D_, D_);
  transpose_bf16<<<dim3(F_/32, D_/32, L_), tb, 0, stream>>>(W1, w1T, D_, F_);
  transpose_bf16<<<dim3(D_/32, F_/32, L_), tb, 0, stream>>>(W2, w2T, F_, D_);
  inproj_kernel<<<SB_, D_, 0, stream>>>(x, Win, bin, pe, h);

  for (int l=0; l<L_; l++){
    ln_kernel<0><<<SB_/4, 256, 0, stream>>>(h, ln1g + l*D_, ln1b + l*D_, yb, nullptr);
    gemm_kernel<0><<<dim3(512,4), 256, 0, stream>>>(yb, wqT + (size_t)l*D_*D_, nullptr, nullptr, qb, D_, D_);
    gemm_kernel<0><<<dim3(512,4), 256, 0, stream>>>(yb, wkT + (size_t)l*D_*D_, nullptr, nullptr, kb, D_, D_);
    gemm_kernel<0><<<dim3(512,4), 256, 0, stream>>>(yb, wvT + (size_t)l*D_*D_, nullptr, nullptr, vb, D_, D_);
    attn_kernel<<<S_*H_, 256, 0, stream>>>(qb, kb, vb, cb);
    gemm_kernel<1><<<dim3(512,4), 256, 0, stream>>>(cb, woT + (size_t)l*D_*D_, bo + l*D_, h, nullptr, D_, D_);
    ln_kernel<0><<<SB_/4, 256, 0, stream>>>(h, ln2g + l*D_, ln2b + l*D_, yb, nullptr);
    gemm_kernel<2><<<dim3(512,16), 256, 0, stream>>>(yb, w1T + (size_t)l*D_*F_, b1 + l*F_, nullptr, act, F_, D_);
    gemm_kernel<1><<<dim3(512,4), 256, 0, stream>>>(act, w2T + (size_t)l*F_*D_, b2 + l*D_, h, nullptr, D_, F_);
  }
  ln_kernel<1><<<SB_/4, 256, 0, stream>>>(h, lnfg, lnfb, nullptr, (float*)d_out);
}

// Round 2
// 5015.860 us; speedup vs baseline: 1.2107x; 1.2107x over previous
//
#include <hip/hip_runtime.h>
#include <math.h>

#define S_ 512
#define B_ 128
#define D_ 512
#define I_ 64
#define F_ 2048
#define H_ 8
#define DK_ 64
#define L_ 4
#define SB_ (S_*B_)

typedef unsigned short u16;
typedef unsigned int u32;
typedef __attribute__((ext_vector_type(4))) unsigned int u32x4;
typedef __attribute__((ext_vector_type(4))) float f32x4;

__device__ __forceinline__ u16 f2bf(float f){
  u32 x = __builtin_bit_cast(u32, f);
  x += 0x7fffu + ((x >> 16) & 1u);
  return (u16)(x >> 16);
}

__device__ __forceinline__ void mfma16(f32x4& c, const u32x4& a, const u32x4& b){
  asm volatile("v_mfma_f32_16x16x32_bf16 %0, %1, %2, %0" : "+v"(c) : "v"(a), "v"(b));
}

// async global->LDS, 16 B per lane (m97 pattern)
__device__ __forceinline__ void gload16(const u16* g, u16* l){
  __builtin_amdgcn_global_load_lds((const __attribute__((address_space(1))) unsigned int*)g,
                                   (__attribute__((address_space(3))) unsigned int*)l, 16, 0, 0);
}

// ---------------- positional encoding table ----------------
__global__ void pe_kernel(float* __restrict__ pe){
  int s = blockIdx.x, d = threadIdx.x;
  float e = expf((float)(d & ~1) * (-9.210340371976184f / (float)D_));
  float arg = (float)s * e;
  pe[s*D_ + d] = (d & 1) ? cosf(arg) : sinf(arg);
}

// ---------------- weight transpose + fp32->bf16 ----------------
// src: [z][R][C] f32. dst: dst + z*zstride, [C][R] bf16 (dst[c][r] = src[r][c])
__global__ void transpose_bf16(const float* __restrict__ src, u16* __restrict__ dst,
                               int R, int C, size_t zstride){
  __shared__ float t[32][33];
  size_t sbase = (size_t)blockIdx.z * R * C;
  size_t dbase = (size_t)blockIdx.z * zstride;
  int r0 = blockIdx.y*32, c0 = blockIdx.x*32;
  int tx = threadIdx.x, ty = threadIdx.y;
  #pragma unroll
  for (int j=0;j<4;j++)
    t[ty+j*8][tx] = src[sbase + (size_t)(r0+ty+j*8)*C + c0+tx];
  __syncthreads();
  #pragma unroll
  for (int j=0;j<4;j++)
    dst[dbase + (size_t)(c0+ty+j*8)*R + r0+tx] = f2bf(t[tx][ty+j*8]);
}

// ---------------- input projection + scale + PE ----------------
__global__ __launch_bounds__(512) void inproj_kernel(const float* __restrict__ x,
    const float* __restrict__ Win, const float* __restrict__ bin,
    const float* __restrict__ pe, float* __restrict__ h){
  int r = blockIdx.x;
  int s = r >> 7, b = r & (B_-1);
  int d = threadIdx.x;
  __shared__ float xs[I_];
  if (d < I_) xs[d] = x[((size_t)b*S_ + s)*I_ + d];
  __syncthreads();
  float acc = 0.f;
  #pragma unroll 16
  for (int i=0;i<I_;i++) acc = fmaf(xs[i], Win[i*D_ + d], acc);
  h[(size_t)r*D_ + d] = (acc + bin[d]) * 22.627416997969522f + pe[s*D_ + d];
}

// ---------------- LayerNorm ----------------
template<int FINAL>
__global__ __launch_bounds__(256) void ln_kernel(const float* __restrict__ hsrc,
    const float* __restrict__ g, const float* __restrict__ bb,
    u16* __restrict__ outb, float* __restrict__ outf){
  int row = blockIdx.x*4 + (threadIdx.x>>6);
  int lane = threadIdx.x & 63;
  const float* hr = hsrc + (size_t)row*D_ + lane*8;
  f32x4 a0 = *(const f32x4*)hr;
  f32x4 a1 = *(const f32x4*)(hr+4);
  float v[8];
  #pragma unroll
  for (int j=0;j<4;j++){ v[j]=a0[j]; v[4+j]=a1[j]; }
  float sum = 0.f;
  #pragma unroll
  for (int j=0;j<8;j++) sum += v[j];
  #pragma unroll
  for (int m=1;m<64;m<<=1) sum += __shfl_xor(sum, m);
  float mean = sum * (1.f/(float)D_);
  float s2 = 0.f;
  #pragma unroll
  for (int j=0;j<8;j++){ float dd = v[j]-mean; s2 = fmaf(dd,dd,s2); }
  #pragma unroll
  for (int m=1;m<64;m<<=1) s2 += __shfl_xor(s2, m);
  float inv = rsqrtf(s2*(1.f/(float)D_) + 1e-5f);
  f32x4 g0 = *(const f32x4*)&g[lane*8];
  f32x4 g1 = *(const f32x4*)&g[lane*8+4];
  f32x4 b0 = *(const f32x4*)&bb[lane*8];
  f32x4 b1 = *(const f32x4*)&bb[lane*8+4];
  float o[8];
  #pragma unroll
  for (int j=0;j<4;j++){
    o[j]   = (v[j]-mean)*inv*g0[j] + b0[j];
    o[4+j] = (v[4+j]-mean)*inv*g1[j] + b1[j];
  }
  if (FINAL == 0){
    u32x4 pk;
    #pragma unroll
    for (int j=0;j<4;j++)
      pk[j] = (u32)f2bf(o[2*j]) | ((u32)f2bf(o[2*j+1])<<16);
    *(u32x4*)&outb[(size_t)row*D_ + lane*8] = pk;
  } else {
    int s = row>>7, b = row&(B_-1);
    float* op = outf + ((size_t)b*S_ + s)*D_ + lane*8;
    f32x4 r0, r1;
    #pragma unroll
    for (int j=0;j<4;j++){ r0[j]=o[j]; r1[j]=o[4+j]; }
    *(f32x4*)op = r0;
    *(f32x4*)(op+4) = r1;
  }
}

// ---------------- bf16 MFMA GEMM, 128x128 tile, global_load_lds (m97) ----------------
// A: (65536, K) bf16 row-major.  Wt: (N, K) bf16 row-major.
// MODE 0: QKV fused N=1536: mat=gn>>9 selects q/k/v (stride 33554432 u16),
//         scatter to [((s*H+hh)*B+b)*64+dd]
// MODE 1: hres[r*512+n] += dot + bias[n]
// MODE 2: outb[r*N+n] = bf16(gelu_exact(dot + bias[n]))
template<int MODE>
__global__ __launch_bounds__(256) void gemm_kernel(const u16* __restrict__ A,
    const u16* __restrict__ Wt, const float* __restrict__ bias,
    float* __restrict__ hres, u16* __restrict__ outb, int N, int K){
  const int m0 = blockIdx.x*128, n0 = blockIdx.y*128;
  __shared__ u16 a_lds[128*32];
  __shared__ u16 b_lds[128*32];
  const int t = threadIdx.x;
  const int lane = t & 63, wave = t >> 6;
  const int wm = wave >> 1, wn = wave & 1;
  const int rsel = lane & 15, kg = (lane>>4)*8;
  // staging coords: per call li: row = t/4 + li*64, col = (t&3)*8
  const u16* ag = A  + (size_t)(m0 + (t>>2))*K + (t&3)*8;
  const u16* bg = Wt + (size_t)(n0 + (t>>2))*K + (t&3)*8;
  f32x4 acc[4][4] = {};
  for (int k0 = 0; k0 < K; k0 += 32){
    asm volatile("s_nop 7\n\ts_nop 7"); // WAR insurance before LDS overwrite
    __syncthreads();
    gload16(ag + k0,            &a_lds[t*8]);
    gload16(ag + 64*(size_t)K + k0, &a_lds[2048 + t*8]);
    gload16(bg + k0,            &b_lds[t*8]);
    gload16(bg + 64*(size_t)K + k0, &b_lds[2048 + t*8]);
    __syncthreads();  // vmcnt drained before barrier -> tiles ready
    u32x4 af[4], bfr[4];
    #pragma unroll
    for (int i=0;i<4;i++){
      af[i]  = *(const u32x4*)&a_lds[(wm*64 + i*16 + rsel)*32 + kg];
      bfr[i] = *(const u32x4*)&b_lds[(wn*64 + i*16 + rsel)*32 + kg];
    }
    #pragma unroll
    for (int i=0;i<4;i++)
      #pragma unroll
      for (int j=0;j<4;j++)
        mfma16(acc[i][j], af[i], bfr[j]);
  }
  asm volatile("s_nop 7\n\ts_nop 7");
  const int rb = (lane>>4)*4;
  #pragma unroll
  for (int i=0;i<4;i++){
    #pragma unroll
    for (int j=0;j<4;j++){
      int gn = n0 + wn*64 + j*16 + rsel;
      #pragma unroll
      for (int rg=0;rg<4;rg++){
        int gr = m0 + wm*64 + i*16 + rb + rg;
        float val = acc[i][j][rg];
        if (MODE == 0){
          int mat = gn >> 9;
          int hh = (gn >> 6) & 7, dd = gn & 63;
          int s = gr >> 7, b = gr & 127;
          u16* dst = outb + (size_t)mat*33554432ull;
          dst[(size_t)((s*H_ + hh)*B_ + b)*DK_ + dd] = f2bf(val);
        } else if (MODE == 1){
          hres[(size_t)gr*D_ + gn] += val + bias[gn];
        } else {
          float xg = val + bias[gn];
          float ge = 0.5f*xg*(1.f + erff(xg*0.7071067811865476f));
          outb[(size_t)gr*(size_t)N + gn] = f2bf(ge);
        }
      }
    }
  }
}

// ---------------- fused batch-attention per (s, head) ----------------
// q,k,v: (S*H, B, DK) bf16. cb: (S*B, D) bf16.
// 76.5 KB LDS -> 2 blocks/CU. Sparse PV: top-12 winners per row, V rows from
// global (16 KB/block panel -> L1-resident).
__global__ __launch_bounds__(256) void attn_kernel(const u16* __restrict__ qb,
    const u16* __restrict__ kb, const u16* __restrict__ vb, u16* __restrict__ cb){
  __shared__ __align__(16) char smem[78336];
  u16* q_lds = (u16*)smem;                 // [128][72]
  u16* k_lds = (u16*)(smem + 18432);       // [128][72]
  float* S   = (float*)smem;               // [128][129] f32, overlays q,k
  u32* wl    = (u32*)(smem + 66048);       // [256][12] packed (bf16 w | idx)
  int sh = blockIdx.x;
  int s = sh >> 3, hh = sh & 7;
  int t = threadIdx.x, lane = t & 63, wave = t >> 6;
  const u16* qg = qb + (size_t)sh * (B_*DK_);
  const u16* kg = kb + (size_t)sh * (B_*DK_);
  const u16* vg = vb + (size_t)sh * (B_*DK_);
  #pragma unroll
  for (int rr=0; rr<4; rr++){
    int idx = rr*2048 + t*8;
    int row = idx >> 6, col = idx & 63;
    *(u32x4*)&q_lds[row*72+col] = *(const u32x4*)&qg[idx];
    *(u32x4*)&k_lds[row*72+col] = *(const u32x4*)&kg[idx];
  }
  __syncthreads();
  int wm = wave>>1, wn = wave&1, rsel = lane & 15;
  f32x4 sacc[4][4] = {};
  #pragma unroll
  for (int ks=0; ks<2; ks++){
    asm volatile("s_nop 7\n\ts_nop 7");
    int ko = ks*32 + (lane>>4)*8;
    u32x4 qf[4], kf[4];
    #pragma unroll
    for (int i=0;i<4;i++){
      qf[i] = *(const u32x4*)&q_lds[(wm*64+i*16+rsel)*72 + ko];
      kf[i] = *(const u32x4*)&k_lds[(wn*64+i*16+rsel)*72 + ko];
    }
    #pragma unroll
    for (int i=0;i<4;i++)
      #pragma unroll
      for (int j=0;j<4;j++)
        mfma16(sacc[i][j], qf[i], kf[j]);
  }
  asm volatile("s_nop 7\n\ts_nop 7");
  __syncthreads();  // MFMA reads of q,k complete before S overlays them
  int rb = (lane>>4)*4;
  #pragma unroll
  for (int i=0;i<4;i++)
    #pragma unroll
    for (int j=0;j<4;j++)
      #pragma unroll
      for (int rg=0;rg<4;rg++)
        S[(wm*64+i*16+rb+rg)*129 + wn*64+j*16+rsel] = sacc[i][j][rg] * 0.125f;
  __syncthreads();
  // ---- per-row top-12 (2 threads/row, 64 elems each) ----
  int r = t >> 1, half = t & 1;
  const float* srow = S + r*129 + half*64;
  float kv[12];
  #pragma unroll
  for (int i=0;i<12;i++) kv[i] = -3.4e38f;
  for (int i=0;i<64;i++){
    float v = srow[i];
    if (v > kv[11]){
      float inc = v;
      #pragma unroll
      for (int p=0;p<12;p++){
        float cur = kv[p];
        bool gt = inc > cur;
        kv[p] = gt ? inc : cur;
        inc   = gt ? cur : inc;
      }
    }
  }
  // merge two sorted-desc 12-lists: kth = min_i max(a[i], b[11-i])
  float kth = 3.4e38f;
  #pragma unroll
  for (int i=0;i<12;i++){
    float pb = __shfl_xor(kv[11-i], 1);
    kth = fminf(kth, fmaxf(kv[i], pb));
  }
  float mx = fmaxf(kv[0], __shfl_xor(kv[0], 1));
  // ---- exp + compact winners (own slots, no atomics, deterministic) ----
  float sum = 0.f;
  int n = 0;
  u32* myw = wl + t*12;
  for (int i=0;i<64;i++){
    float v = srow[i];
    if (v >= kth && n < 12){
      float e = __expf(v - mx);
      sum += e;
      myw[n] = ((u32)f2bf(e) << 16) | (u32)(half*64 + i);
      n++;
    }
  }
  float tsum = sum + __shfl_xor(sum, 1);
  // ---- sparse PV: ctx[r] = sum_w w * V[c] ----
  float facc[64];
  #pragma unroll
  for (int d=0; d<64; d++) facc[d] = 0.f;
  for (int j=0; j<n; j++){
    u32 e = myw[j];
    float w = __builtin_bit_cast(float, e & 0xffff0000u);
    const u32x4* vr = (const u32x4*)(vg + (size_t)(e & 0xffffu)*DK_);
    #pragma unroll
    for (int q8=0;q8<8;q8++){
      u32x4 u = vr[q8];
      #pragma unroll
      for (int z=0;z<4;z++){
        float lo = __builtin_bit_cast(float, u[z] << 16);
        float hi = __builtin_bit_cast(float, u[z] & 0xffff0000u);
        facc[q8*8+z*2]   = fmaf(w, lo, facc[q8*8+z*2]);
        facc[q8*8+z*2+1] = fmaf(w, hi, facc[q8*8+z*2+1]);
      }
    }
  }
  float inv = 1.f / tsum;
  #pragma unroll
  for (int d=0; d<64; d++)
    facc[d] = (facc[d] + __shfl_xor(facc[d], 1)) * inv;
  u16* orow = cb + ((size_t)(s*B_ + r))*D_ + hh*DK_ + half*32;
  #pragma unroll
  for (int q4=0; q4<4; q4++){
    u32x4 pkk;
    #pragma unroll
    for (int z=0; z<4; z++){
      int d = half*32 + q4*8 + z*2;
      pkk[z] = (u32)f2bf(facc[d]) | ((u32)f2bf(facc[d+1]) << 16);
    }
    *(u32x4*)(orow + q4*8) = pkk;
  }
}

extern "C" void kernel_launch(void* const* d_in, const int* in_sizes, int n_in,
                              void* d_out, int out_size, void* d_ws, size_t ws_size,
                              hipStream_t stream) {
  const float* x    = (const float*)d_in[0];
  const float* Win  = (const float*)d_in[1];
  const float* bin  = (const float*)d_in[2];
  const float* ln1g = (const float*)d_in[3];
  const float* ln1b = (const float*)d_in[4];
  const float* Wq   = (const float*)d_in[5];
  const float* Wk   = (const float*)d_in[6];
  const float* Wv   = (const float*)d_in[7];
  const float* Wo   = (const float*)d_in[8];
  const float* bo   = (const float*)d_in[9];
  const float* ln2g = (const float*)d_in[10];
  const float* ln2b = (const float*)d_in[11];
  const float* W1   = (const float*)d_in[12];
  const float* b1   = (const float*)d_in[13];
  const float* W2   = (const float*)d_in[14];
  const float* b2   = (const float*)d_in[15];
  const float* lnfg = (const float*)d_in[16];
  const float* lnfb = (const float*)d_in[17];

  char* ws = (char*)d_ws;
  float* h  = (float*)(ws);                      // 134217728 B
  u16* yb   = (u16*)(ws + 134217728ull);         // 67108864 B
  u16* qb   = (u16*)(ws + 201326592ull);         // 67108864 B (kb, vb contiguous)
  u16* cb   = (u16*)(ws + 402653184ull);
  u16* act  = qb;                                // overlays qb..cb (268435456 B)
  u16* kb   = (u16*)(ws + 268435456ull);
  u16* vb   = (u16*)(ws + 335544320ull);
  u16* wqkvT= (u16*)(ws + 469762048ull);         // [L][3][D][D] = 6 MB
  u16* woT  = (u16*)(ws + 476053504ull);         // [L][D][D] = 2 MB
  u16* w1T  = (u16*)(ws + 478150656ull);         // [L][F][D... [L] D*F = 8 MB
  u16* w2T  = (u16*)(ws + 486539264ull);         // 8 MB
  float* pe = (float*)(ws + 494927872ull);       // 1 MB

  dim3 tb(32,8);
  pe_kernel<<<S_, D_, 0, stream>>>(pe);
  transpose_bf16<<<dim3(D_/32, D_/32, L_), tb, 0, stream>>>(Wq, wqkvT,            D_, D_, (size_t)3*D_*D_);
  transpose_bf16<<<dim3(D_/32, D_/32, L_), tb, 0, stream>>>(Wk, wqkvT + D_*D_,    D_, D_, (size_t)3*D_*D_);
  transpose_bf16<<<dim3(D_/32, D_/32, L_), tb, 0, stream>>>(Wv, wqkvT + 2*D_*D_,  D_, D_, (size_t)3*D_*D_);
  transpose_bf16<<<dim3(D_/32, D_/32, L_), tb, 0, stream>>>(Wo, woT,              D_, D_, (size_t)D_*D_);
  transpose_bf16<<<dim3(F_/32, D_/32, L_), tb, 0, stream>>>(W1, w1T, D_, F_, (size_t)D_*F_);
  transpose_bf16<<<dim3(D_/32, F_/32, L_), tb, 0, stream>>>(W2, w2T, F_, D_, (size_t)F_*D_);
  inproj_kernel<<<SB_, D_, 0, stream>>>(x, Win, bin, pe, h);

  for (int l=0; l<L_; l++){
    ln_kernel<0><<<SB_/4, 256, 0, stream>>>(h, ln1g + l*D_, ln1b + l*D_, yb, nullptr);
    gemm_kernel<0><<<dim3(512,12), 256, 0, stream>>>(yb, wqkvT + (size_t)l*3*D_*D_, nullptr, nullptr, qb, 1536, D_);
    attn_kernel<<<S_*H_, 256, 0, stream>>>(qb, kb, vb, cb);
    gemm_kernel<1><<<dim3(512,4), 256, 0, stream>>>(cb, woT + (size_t)l*D_*D_, bo + l*D_, h, nullptr, D_, D_);
    ln_kernel<0><<<SB_/4, 256, 0, stream>>>(h, ln2g + l*D_, ln2b + l*D_, yb, nullptr);
    gemm_kernel<2><<<dim3(512,16), 256, 0, stream>>>(yb, w1T + (size_t)l*D_*F_, b1 + l*F_, nullptr, act, F_, D_);
    gemm_kernel<1><<<dim3(512,4), 256, 0, stream>>>(act, w2T + (size_t)l*F_*D_, b2 + l*D_, h, nullptr, D_, F_);
  }
  ln_kernel<1><<<SB_/4, 256, 0, stream>>>(h, lnfg, lnfb, nullptr, (float*)d_out);
}

// Round 3
// 4440.980 us; speedup vs baseline: 1.3674x; 1.1294x over previous
//
#include <hip/hip_runtime.h>
#include <math.h>

#define S_ 512
#define B_ 128
#define D_ 512
#define I_ 64
#define F_ 2048
#define H_ 8
#define DK_ 64
#define L_ 4
#define SB_ (S_*B_)

typedef unsigned short u16;
typedef unsigned int u32;
typedef __attribute__((ext_vector_type(4))) unsigned int u32x4;
typedef __attribute__((ext_vector_type(4))) float f32x4;

__device__ __forceinline__ u16 f2bf(float f){
  u32 x = __builtin_bit_cast(u32, f);
  x += 0x7fffu + ((x >> 16) & 1u);
  return (u16)(x >> 16);
}

__device__ __forceinline__ void mfma16(f32x4& c, const u32x4& a, const u32x4& b){
  asm volatile("v_mfma_f32_16x16x32_bf16 %0, %1, %2, %0" : "+v"(c) : "v"(a), "v"(b));
}

// async global->LDS, 16 B per lane (m97 pattern)
__device__ __forceinline__ void gload16(const u16* g, u16* l){
  __builtin_amdgcn_global_load_lds((const __attribute__((address_space(1))) unsigned int*)g,
                                   (__attribute__((address_space(3))) unsigned int*)l, 16, 0, 0);
}

// ---------------- positional encoding table ----------------
__global__ void pe_kernel(float* __restrict__ pe){
  int s = blockIdx.x, d = threadIdx.x;
  float e = expf((float)(d & ~1) * (-9.210340371976184f / (float)D_));
  float arg = (float)s * e;
  pe[s*D_ + d] = (d & 1) ? cosf(arg) : sinf(arg);
}

// ---------------- weight transpose + fp32->bf16 ----------------
__global__ void transpose_bf16(const float* __restrict__ src, u16* __restrict__ dst,
                               int R, int C, size_t zstride){
  __shared__ float t[32][33];
  size_t sbase = (size_t)blockIdx.z * R * C;
  size_t dbase = (size_t)blockIdx.z * zstride;
  int r0 = blockIdx.y*32, c0 = blockIdx.x*32;
  int tx = threadIdx.x, ty = threadIdx.y;
  #pragma unroll
  for (int j=0;j<4;j++)
    t[ty+j*8][tx] = src[sbase + (size_t)(r0+ty+j*8)*C + c0+tx];
  __syncthreads();
  #pragma unroll
  for (int j=0;j<4;j++)
    dst[dbase + (size_t)(c0+ty+j*8)*R + r0+tx] = f2bf(t[tx][ty+j*8]);
}

// ---------------- input projection + scale + PE ----------------
__global__ __launch_bounds__(512) void inproj_kernel(const float* __restrict__ x,
    const float* __restrict__ Win, const float* __restrict__ bin,
    const float* __restrict__ pe, float* __restrict__ h){
  int r = blockIdx.x;
  int s = r >> 7, b = r & (B_-1);
  int d = threadIdx.x;
  __shared__ float xs[I_];
  if (d < I_) xs[d] = x[((size_t)b*S_ + s)*I_ + d];
  __syncthreads();
  float acc = 0.f;
  #pragma unroll 16
  for (int i=0;i<I_;i++) acc = fmaf(xs[i], Win[i*D_ + d], acc);
  h[(size_t)r*D_ + d] = (acc + bin[d]) * 22.627416997969522f + pe[s*D_ + d];
}

// ---------------- LayerNorm ----------------
template<int FINAL>
__global__ __launch_bounds__(256) void ln_kernel(const float* __restrict__ hsrc,
    const float* __restrict__ g, const float* __restrict__ bb,
    u16* __restrict__ outb, float* __restrict__ outf){
  int row = blockIdx.x*4 + (threadIdx.x>>6);
  int lane = threadIdx.x & 63;
  const float* hr = hsrc + (size_t)row*D_ + lane*8;
  f32x4 a0 = *(const f32x4*)hr;
  f32x4 a1 = *(const f32x4*)(hr+4);
  float v[8];
  #pragma unroll
  for (int j=0;j<4;j++){ v[j]=a0[j]; v[4+j]=a1[j]; }
  float sum = 0.f;
  #pragma unroll
  for (int j=0;j<8;j++) sum += v[j];
  #pragma unroll
  for (int m=1;m<64;m<<=1) sum += __shfl_xor(sum, m);
  float mean = sum * (1.f/(float)D_);
  float s2 = 0.f;
  #pragma unroll
  for (int j=0;j<8;j++){ float dd = v[j]-mean; s2 = fmaf(dd,dd,s2); }
  #pragma unroll
  for (int m=1;m<64;m<<=1) s2 += __shfl_xor(s2, m);
  float inv = rsqrtf(s2*(1.f/(float)D_) + 1e-5f);
  f32x4 g0 = *(const f32x4*)&g[lane*8];
  f32x4 g1 = *(const f32x4*)&g[lane*8+4];
  f32x4 b0 = *(const f32x4*)&bb[lane*8];
  f32x4 b1 = *(const f32x4*)&bb[lane*8+4];
  float o[8];
  #pragma unroll
  for (int j=0;j<4;j++){
    o[j]   = (v[j]-mean)*inv*g0[j] + b0[j];
    o[4+j] = (v[4+j]-mean)*inv*g1[j] + b1[j];
  }
  if (FINAL == 0){
    u32x4 pk;
    #pragma unroll
    for (int j=0;j<4;j++)
      pk[j] = (u32)f2bf(o[2*j]) | ((u32)f2bf(o[2*j+1])<<16);
    *(u32x4*)&outb[(size_t)row*D_ + lane*8] = pk;
  } else {
    int s = row>>7, b = row&(B_-1);
    float* op = outf + ((size_t)b*S_ + s)*D_ + lane*8;
    f32x4 r0, r1;
    #pragma unroll
    for (int j=0;j<4;j++){ r0[j]=o[j]; r1[j]=o[4+j]; }
    *(f32x4*)op = r0;
    *(f32x4*)(op+4) = r1;
  }
}

// ---------------- bf16 MFMA GEMM, 128x128 tile, global_load_lds (m97) ----------------
// Grid: (n_tiles, m_tiles) — n fastest so consecutive blocks share the A panel
// (L2 hits); XCD chunk swizzle keeps panel-sharing blocks on one XCD L2.
// MODE 0: QKV fused N=1536; MODE 1: residual += ; MODE 2: gelu->bf16
template<int MODE>
__global__ __launch_bounds__(256) void gemm_kernel(const u16* __restrict__ A,
    const u16* __restrict__ Wt, const float* __restrict__ bias,
    float* __restrict__ hres, u16* __restrict__ outb, int N, int K){
  const u32 nwg = gridDim.x * gridDim.y;
  u32 wg = blockIdx.y * gridDim.x + blockIdx.x;
  wg = (wg & 7) * (nwg >> 3) + (wg >> 3);   // bijective XCD chunk swizzle (nwg%8==0)
  const int m0 = (int)(wg / gridDim.x) * 128;
  const int n0 = (int)(wg % gridDim.x) * 128;
  __shared__ u16 a_lds[128*32];
  __shared__ u16 b_lds[128*32];
  const int t = threadIdx.x;
  const int lane = t & 63, wave = t >> 6;
  const int wm = wave >> 1, wn = wave & 1;
  const int rsel = lane & 15, kg = (lane>>4)*8;
  const u16* ag = A  + (size_t)(m0 + (t>>2))*K + (t&3)*8;
  const u16* bg = Wt + (size_t)(n0 + (t>>2))*K + (t&3)*8;
  f32x4 acc[4][4] = {};
  for (int k0 = 0; k0 < K; k0 += 32){
    asm volatile("s_nop 7\n\ts_nop 7"); // WAR insurance before LDS overwrite
    __syncthreads();
    gload16(ag + k0,                &a_lds[t*8]);
    gload16(ag + 64*(size_t)K + k0, &a_lds[2048 + t*8]);
    gload16(bg + k0,                &b_lds[t*8]);
    gload16(bg + 64*(size_t)K + k0, &b_lds[2048 + t*8]);
    __syncthreads();
    u32x4 af[4], bfr[4];
    #pragma unroll
    for (int i=0;i<4;i++){
      af[i]  = *(const u32x4*)&a_lds[(wm*64 + i*16 + rsel)*32 + kg];
      bfr[i] = *(const u32x4*)&b_lds[(wn*64 + i*16 + rsel)*32 + kg];
    }
    #pragma unroll
    for (int i=0;i<4;i++)
      #pragma unroll
      for (int j=0;j<4;j++)
        mfma16(acc[i][j], af[i], bfr[j]);
  }
  asm volatile("s_nop 7\n\ts_nop 7");
  const int rb = (lane>>4)*4;
  #pragma unroll
  for (int i=0;i<4;i++){
    #pragma unroll
    for (int j=0;j<4;j++){
      int gn = n0 + wn*64 + j*16 + rsel;
      #pragma unroll
      for (int rg=0;rg<4;rg++){
        int gr = m0 + wm*64 + i*16 + rb + rg;
        float val = acc[i][j][rg];
        if (MODE == 0){
          int mat = gn >> 9;
          int hh = (gn >> 6) & 7, dd = gn & 63;
          int s = gr >> 7, b = gr & 127;
          u16* dst = outb + (size_t)mat*33554432ull;
          dst[(size_t)((s*H_ + hh)*B_ + b)*DK_ + dd] = f2bf(val);
        } else if (MODE == 1){
          hres[(size_t)gr*D_ + gn] += val + bias[gn];
        } else {
          float xg = val + bias[gn];
          float ge = 0.5f*xg*(1.f + erff(xg*0.7071067811865476f));
          outb[(size_t)gr*(size_t)N + gn] = f2bf(ge);
        }
      }
    }
  }
}

// ---------------- fused batch-attention per (s, head) ----------------
// 78 KB LDS -> 2 blocks/CU. launch_bounds(256,2) so PV accumulator stays in
// VGPRs (r1 spilled at default occupancy target: 530 MB scratch writes).
__global__ __launch_bounds__(256, 2) void attn_kernel(const u16* __restrict__ qb,
    const u16* __restrict__ kb, const u16* __restrict__ vb, u16* __restrict__ cb){
  __shared__ __align__(16) char smem[79872];
  u16* q_lds = (u16*)smem;                 // [128][72]
  u16* k_lds = (u16*)(smem + 18432);       // [128][72]
  float* S   = (float*)smem;               // [128][132] f32, overlays q,k
  u32* wl    = (u32*)(smem + 67584);       // [256][12] packed (bf16 w | idx)
  int sh = blockIdx.x;
  int s = sh >> 3, hh = sh & 7;
  int t = threadIdx.x, lane = t & 63, wave = t >> 6;
  const u16* qg = qb + (size_t)sh * (B_*DK_);
  const u16* kg = kb + (size_t)sh * (B_*DK_);
  const u16* vg = vb + (size_t)sh * (B_*DK_);
  #pragma unroll
  for (int rr=0; rr<4; rr++){
    int idx = rr*2048 + t*8;
    int row = idx >> 6, col = idx & 63;
    *(u32x4*)&q_lds[row*72+col] = *(const u32x4*)&qg[idx];
    *(u32x4*)&k_lds[row*72+col] = *(const u32x4*)&kg[idx];
  }
  __syncthreads();
  int wm = wave>>1, wn = wave&1, rsel = lane & 15;
  f32x4 sacc[4][4] = {};
  #pragma unroll
  for (int ks=0; ks<2; ks++){
    asm volatile("s_nop 7\n\ts_nop 7");
    int ko = ks*32 + (lane>>4)*8;
    u32x4 qf[4], kf[4];
    #pragma unroll
    for (int i=0;i<4;i++){
      qf[i] = *(const u32x4*)&q_lds[(wm*64+i*16+rsel)*72 + ko];
      kf[i] = *(const u32x4*)&k_lds[(wn*64+i*16+rsel)*72 + ko];
    }
    #pragma unroll
    for (int i=0;i<4;i++)
      #pragma unroll
      for (int j=0;j<4;j++)
        mfma16(sacc[i][j], qf[i], kf[j]);
  }
  asm volatile("s_nop 7\n\ts_nop 7");
  __syncthreads();  // MFMA reads of q,k complete before S overlays them
  int rb = (lane>>4)*4;
  #pragma unroll
  for (int i=0;i<4;i++)
    #pragma unroll
    for (int j=0;j<4;j++)
      #pragma unroll
      for (int rg=0;rg<4;rg++)
        S[(wm*64+i*16+rb+rg)*132 + wn*64+j*16+rsel] = sacc[i][j][rg] * 0.125f;
  __syncthreads();
  // ---- per-row top-12 (2 threads/row, 64 elems each), vectorized reads ----
  int r = t >> 1, half = t & 1;
  const f32x4* srow4 = (const f32x4*)(S + r*132 + half*64);
  float kv[12];
  #pragma unroll
  for (int i=0;i<12;i++) kv[i] = -3.4e38f;
  for (int i4=0;i4<16;i4++){
    f32x4 v4 = srow4[i4];
    float m4 = fmaxf(fmaxf(v4[0],v4[1]), fmaxf(v4[2],v4[3]));
    if (m4 > kv[11]){
      #pragma unroll
      for (int z=0; z<4; z++){
        float inc = v4[z];
        if (inc > kv[11]){
          #pragma unroll
          for (int p=0;p<12;p++){
            float cur = kv[p];
            bool gt = inc > cur;
            kv[p] = gt ? inc : cur;
            inc   = gt ? cur : inc;
          }
        }
      }
    }
  }
  // merge two sorted-desc 12-lists: kth = min_i max(a[i], b[11-i])
  float kth = 3.4e38f;
  #pragma unroll
  for (int i=0;i<12;i++){
    float pb = __shfl_xor(kv[11-i], 1);
    kth = fminf(kth, fmaxf(kv[i], pb));
  }
  float mx = fmaxf(kv[0], __shfl_xor(kv[0], 1));
  // ---- exp + compact winners ----
  float sum = 0.f;
  int n = 0;
  u32* myw = wl + t*12;
  for (int i4=0;i4<16;i4++){
    f32x4 v4 = srow4[i4];
    #pragma unroll
    for (int z=0; z<4; z++){
      float v = v4[z];
      if (v >= kth && n < 12){
        float e = __expf(v - mx);
        sum += e;
        myw[n] = ((u32)f2bf(e) << 16) | (u32)(half*64 + i4*4 + z);
        n++;
      }
    }
  }
  float tsum = sum + __shfl_xor(sum, 1);
  // ---- sparse PV: ctx[r] = sum_w w * V[c] ----
  float facc[64];
  #pragma unroll
  for (int d=0; d<64; d++) facc[d] = 0.f;
  for (int j=0; j<n; j++){
    u32 e = myw[j];
    float w = __builtin_bit_cast(float, e & 0xffff0000u);
    const u32x4* vr = (const u32x4*)(vg + (size_t)(e & 0xffffu)*DK_);
    #pragma unroll
    for (int q8=0;q8<8;q8++){
      u32x4 u = vr[q8];
      #pragma unroll
      for (int z=0;z<4;z++){
        float lo = __builtin_bit_cast(float, u[z] << 16);
        float hi = __builtin_bit_cast(float, u[z] & 0xffff0000u);
        facc[q8*8+z*2]   = fmaf(w, lo, facc[q8*8+z*2]);
        facc[q8*8+z*2+1] = fmaf(w, hi, facc[q8*8+z*2+1]);
      }
    }
  }
  float inv = 1.f / tsum;
  #pragma unroll
  for (int d=0; d<64; d++)
    facc[d] = (facc[d] + __shfl_xor(facc[d], 1)) * inv;
  u16* orow = cb + ((size_t)(s*B_ + r))*D_ + hh*DK_ + half*32;
  #pragma unroll
  for (int q4=0; q4<4; q4++){
    u32x4 pkk;
    #pragma unroll
    for (int z=0; z<4; z++){
      int d = half*32 + q4*8 + z*2;
      pkk[z] = (u32)f2bf(facc[d]) | ((u32)f2bf(facc[d+1]) << 16);
    }
    *(u32x4*)(orow + q4*8) = pkk;
  }
}

extern "C" void kernel_launch(void* const* d_in, const int* in_sizes, int n_in,
                              void* d_out, int out_size, void* d_ws, size_t ws_size,
                              hipStream_t stream) {
  const float* x    = (const float*)d_in[0];
  const float* Win  = (const float*)d_in[1];
  const float* bin  = (const float*)d_in[2];
  const float* ln1g = (const float*)d_in[3];
  const float* ln1b = (const float*)d_in[4];
  const float* Wq   = (const float*)d_in[5];
  const float* Wk   = (const float*)d_in[6];
  const float* Wv   = (const float*)d_in[7];
  const float* Wo   = (const float*)d_in[8];
  const float* bo   = (const float*)d_in[9];
  const float* ln2g = (const float*)d_in[10];
  const float* ln2b = (const float*)d_in[11];
  const float* W1   = (const float*)d_in[12];
  const float* b1   = (const float*)d_in[13];
  const float* W2   = (const float*)d_in[14];
  const float* b2   = (const float*)d_in[15];
  const float* lnfg = (const float*)d_in[16];
  const float* lnfb = (const float*)d_in[17];

  char* ws = (char*)d_ws;
  float* h  = (float*)(ws);                      // 134217728 B
  u16* yb   = (u16*)(ws + 134217728ull);         // 67108864 B
  u16* qb   = (u16*)(ws + 201326592ull);         // q,k,v contiguous
  u16* kb   = (u16*)(ws + 268435456ull);
  u16* vb   = (u16*)(ws + 335544320ull);
  u16* cb   = (u16*)(ws + 402653184ull);
  u16* act  = qb;                                // overlays qb..cb
  u16* wqkvT= (u16*)(ws + 469762048ull);         // [L][3][D][D] = 6 MB
  u16* woT  = (u16*)(ws + 476053504ull);         // [L][D][D] = 2 MB
  u16* w1T  = (u16*)(ws + 478150656ull);         // 8 MB
  u16* w2T  = (u16*)(ws + 486539264ull);         // 8 MB
  float* pe = (float*)(ws + 494927872ull);       // 1 MB

  dim3 tb(32,8);
  pe_kernel<<<S_, D_, 0, stream>>>(pe);
  transpose_bf16<<<dim3(D_/32, D_/32, L_), tb, 0, stream>>>(Wq, wqkvT,            D_, D_, (size_t)3*D_*D_);
  transpose_bf16<<<dim3(D_/32, D_/32, L_), tb, 0, stream>>>(Wk, wqkvT + D_*D_,    D_, D_, (size_t)3*D_*D_);
  transpose_bf16<<<dim3(D_/32, D_/32, L_), tb, 0, stream>>>(Wv, wqkvT + 2*D_*D_,  D_, D_, (size_t)3*D_*D_);
  transpose_bf16<<<dim3(D_/32, D_/32, L_), tb, 0, stream>>>(Wo, woT,              D_, D_, (size_t)D_*D_);
  transpose_bf16<<<dim3(F_/32, D_/32, L_), tb, 0, stream>>>(W1, w1T, D_, F_, (size_t)D_*F_);
  transpose_bf16<<<dim3(D_/32, F_/32, L_), tb, 0, stream>>>(W2, w2T, F_, D_, (size_t)F_*D_);
  inproj_kernel<<<SB_, D_, 0, stream>>>(x, Win, bin, pe, h);

  for (int l=0; l<L_; l++){
    ln_kernel<0><<<SB_/4, 256, 0, stream>>>(h, ln1g + l*D_, ln1b + l*D_, yb, nullptr);
    gemm_kernel<0><<<dim3(12,512), 256, 0, stream>>>(yb, wqkvT + (size_t)l*3*D_*D_, nullptr, nullptr, qb, 1536, D_);
    attn_kernel<<<S_*H_, 256, 0, stream>>>(qb, kb, vb, cb);
    gemm_kernel<1><<<dim3(4,512), 256, 0, stream>>>(cb, woT + (size_t)l*D_*D_, bo + l*D_, h, nullptr, D_, D_);
    ln_kernel<0><<<SB_/4, 256, 0, stream>>>(h, ln2g + l*D_, ln2b + l*D_, yb, nullptr);
    gemm_kernel<2><<<dim3(16,512), 256, 0, stream>>>(yb, w1T + (size_t)l*D_*F_, b1 + l*F_, nullptr, act, F_, D_);
    gemm_kernel<1><<<dim3(4,512), 256, 0, stream>>>(act, w2T + (size_t)l*F_*D_, b2 + l*D_, h, nullptr, D_, F_);
  }
  ln_kernel<1><<<SB_/4, 256, 0, stream>>>(h, lnfg, lnfb, nullptr, (float*)d_out);
}

// Round 4
// 4063.837 us; speedup vs baseline: 1.4943x; 1.0928x over previous
//
#include <hip/hip_runtime.h>
#include <math.h>

#define S_ 512
#define B_ 128
#define D_ 512
#define I_ 64
#define F_ 2048
#define H_ 8
#define DK_ 64
#define L_ 4
#define SB_ (S_*B_)

typedef unsigned short u16;
typedef unsigned int u32;
typedef __attribute__((ext_vector_type(4))) unsigned int u32x4;
typedef __attribute__((ext_vector_type(4))) float f32x4;

__device__ __forceinline__ u16 f2bf(float f){
  u32 x = __builtin_bit_cast(u32, f);
  x += 0x7fffu + ((x >> 16) & 1u);
  return (u16)(x >> 16);
}

__device__ __forceinline__ void mfma16(f32x4& c, const u32x4& a, const u32x4& b){
  asm volatile("v_mfma_f32_16x16x32_bf16 %0, %1, %2, %0" : "+v"(c) : "v"(a), "v"(b));
}

// async global->LDS, 16 B per lane (m97 pattern)
__device__ __forceinline__ void gload16(const u16* g, u16* l){
  __builtin_amdgcn_global_load_lds((const __attribute__((address_space(1))) unsigned int*)g,
                                   (__attribute__((address_space(3))) unsigned int*)l, 16, 0, 0);
}

// ---------------- positional encoding table ----------------
__global__ void pe_kernel(float* __restrict__ pe){
  int s = blockIdx.x, d = threadIdx.x;
  float e = expf((float)(d & ~1) * (-9.210340371976184f / (float)D_));
  float arg = (float)s * e;
  pe[s*D_ + d] = (d & 1) ? cosf(arg) : sinf(arg);
}

// ---------------- weight transpose + fp32->bf16 ----------------
__global__ void transpose_bf16(const float* __restrict__ src, u16* __restrict__ dst,
                               int R, int C, size_t zstride){
  __shared__ float t[32][33];
  size_t sbase = (size_t)blockIdx.z * R * C;
  size_t dbase = (size_t)blockIdx.z * zstride;
  int r0 = blockIdx.y*32, c0 = blockIdx.x*32;
  int tx = threadIdx.x, ty = threadIdx.y;
  #pragma unroll
  for (int j=0;j<4;j++)
    t[ty+j*8][tx] = src[sbase + (size_t)(r0+ty+j*8)*C + c0+tx];
  __syncthreads();
  #pragma unroll
  for (int j=0;j<4;j++)
    dst[dbase + (size_t)(c0+ty+j*8)*R + r0+tx] = f2bf(t[tx][ty+j*8]);
}

// ---------------- input projection + scale + PE ----------------
__global__ __launch_bounds__(512) void inproj_kernel(const float* __restrict__ x,
    const float* __restrict__ Win, const float* __restrict__ bin,
    const float* __restrict__ pe, float* __restrict__ h){
  int r = blockIdx.x;
  int s = r >> 7, b = r & (B_-1);
  int d = threadIdx.x;
  __shared__ float xs[I_];
  if (d < I_) xs[d] = x[((size_t)b*S_ + s)*I_ + d];
  __syncthreads();
  float acc = 0.f;
  #pragma unroll 16
  for (int i=0;i<I_;i++) acc = fmaf(xs[i], Win[i*D_ + d], acc);
  h[(size_t)r*D_ + d] = (acc + bin[d]) * 22.627416997969522f + pe[s*D_ + d];
}

// ---------------- LayerNorm ----------------
template<int FINAL>
__global__ __launch_bounds__(256) void ln_kernel(const float* __restrict__ hsrc,
    const float* __restrict__ g, const float* __restrict__ bb,
    u16* __restrict__ outb, float* __restrict__ outf){
  int row = blockIdx.x*4 + (threadIdx.x>>6);
  int lane = threadIdx.x & 63;
  const float* hr = hsrc + (size_t)row*D_ + lane*8;
  f32x4 a0 = *(const f32x4*)hr;
  f32x4 a1 = *(const f32x4*)(hr+4);
  float v[8];
  #pragma unroll
  for (int j=0;j<4;j++){ v[j]=a0[j]; v[4+j]=a1[j]; }
  float sum = 0.f;
  #pragma unroll
  for (int j=0;j<8;j++) sum += v[j];
  #pragma unroll
  for (int m=1;m<64;m<<=1) sum += __shfl_xor(sum, m);
  float mean = sum * (1.f/(float)D_);
  float s2 = 0.f;
  #pragma unroll
  for (int j=0;j<8;j++){ float dd = v[j]-mean; s2 = fmaf(dd,dd,s2); }
  #pragma unroll
  for (int m=1;m<64;m<<=1) s2 += __shfl_xor(s2, m);
  float inv = rsqrtf(s2*(1.f/(float)D_) + 1e-5f);
  f32x4 g0 = *(const f32x4*)&g[lane*8];
  f32x4 g1 = *(const f32x4*)&g[lane*8+4];
  f32x4 b0 = *(const f32x4*)&bb[lane*8];
  f32x4 b1 = *(const f32x4*)&bb[lane*8+4];
  float o[8];
  #pragma unroll
  for (int j=0;j<4;j++){
    o[j]   = (v[j]-mean)*inv*g0[j] + b0[j];
    o[4+j] = (v[4+j]-mean)*inv*g1[j] + b1[j];
  }
  if (FINAL == 0){
    u32x4 pk;
    #pragma unroll
    for (int j=0;j<4;j++)
      pk[j] = (u32)f2bf(o[2*j]) | ((u32)f2bf(o[2*j+1])<<16);
    *(u32x4*)&outb[(size_t)row*D_ + lane*8] = pk;
  } else {
    int s = row>>7, b = row&(B_-1);
    float* op = outf + ((size_t)b*S_ + s)*D_ + lane*8;
    f32x4 r0, r1;
    #pragma unroll
    for (int j=0;j<4;j++){ r0[j]=o[j]; r1[j]=o[4+j]; }
    *(f32x4*)op = r0;
    *(f32x4*)(op+4) = r1;
  }
}

// ---------------- bf16 MFMA GEMM, 128x128 tile, global_load_lds (m97) ----------------
// Grid: (n_tiles, m_tiles) — n fastest so consecutive blocks share the A panel
// (L2 hits); XCD chunk swizzle keeps panel-sharing blocks on one XCD L2.
// MODE 0: QKV fused N=1536; MODE 1: residual += ; MODE 2: gelu->bf16
template<int MODE>
__global__ __launch_bounds__(256) void gemm_kernel(const u16* __restrict__ A,
    const u16* __restrict__ Wt, const float* __restrict__ bias,
    float* __restrict__ hres, u16* __restrict__ outb, int N, int K){
  const u32 nwg = gridDim.x * gridDim.y;
  u32 wg = blockIdx.y * gridDim.x + blockIdx.x;
  wg = (wg & 7) * (nwg >> 3) + (wg >> 3);   // bijective XCD chunk swizzle (nwg%8==0)
  const int m0 = (int)(wg / gridDim.x) * 128;
  const int n0 = (int)(wg % gridDim.x) * 128;
  __shared__ u16 a_lds[128*32];
  __shared__ u16 b_lds[128*32];
  const int t = threadIdx.x;
  const int lane = t & 63, wave = t >> 6;
  const int wm = wave >> 1, wn = wave & 1;
  const int rsel = lane & 15, kg = (lane>>4)*8;
  const u16* ag = A  + (size_t)(m0 + (t>>2))*K + (t&3)*8;
  const u16* bg = Wt + (size_t)(n0 + (t>>2))*K + (t&3)*8;
  f32x4 acc[4][4] = {};
  for (int k0 = 0; k0 < K; k0 += 32){
    asm volatile("s_nop 7\n\ts_nop 7"); // WAR insurance before LDS overwrite
    __syncthreads();
    gload16(ag + k0,                &a_lds[t*8]);
    gload16(ag + 64*(size_t)K + k0, &a_lds[2048 + t*8]);
    gload16(bg + k0,                &b_lds[t*8]);
    gload16(bg + 64*(size_t)K + k0, &b_lds[2048 + t*8]);
    __syncthreads();
    u32x4 af[4], bfr[4];
    #pragma unroll
    for (int i=0;i<4;i++){
      af[i]  = *(const u32x4*)&a_lds[(wm*64 + i*16 + rsel)*32 + kg];
      bfr[i] = *(const u32x4*)&b_lds[(wn*64 + i*16 + rsel)*32 + kg];
    }
    #pragma unroll
    for (int i=0;i<4;i++)
      #pragma unroll
      for (int j=0;j<4;j++)
        mfma16(acc[i][j], af[i], bfr[j]);
  }
  asm volatile("s_nop 7\n\ts_nop 7");
  const int rb = (lane>>4)*4;
  #pragma unroll
  for (int i=0;i<4;i++){
    #pragma unroll
    for (int j=0;j<4;j++){
      int gn = n0 + wn*64 + j*16 + rsel;
      #pragma unroll
      for (int rg=0;rg<4;rg++){
        int gr = m0 + wm*64 + i*16 + rb + rg;
        float val = acc[i][j][rg];
        if (MODE == 0){
          int mat = gn >> 9;
          int hh = (gn >> 6) & 7, dd = gn & 63;
          int s = gr >> 7, b = gr & 127;
          u16* dst = outb + (size_t)mat*33554432ull;
          dst[(size_t)((s*H_ + hh)*B_ + b)*DK_ + dd] = f2bf(val);
        } else if (MODE == 1){
          hres[(size_t)gr*D_ + gn] += val + bias[gn];
        } else {
          float xg = val + bias[gn];
          float ge = 0.5f*xg*(1.f + erff(xg*0.7071067811865476f));
          outb[(size_t)gr*(size_t)N + gn] = f2bf(ge);
        }
      }
    }
  }
}

// ---------------- fused batch-attention per (s, head) ----------------
// 78 KB LDS -> 2 blocks/CU. ALL accumulator arrays statically indexed
// (rule #20: runtime-indexed VGPR arrays go to scratch -> 480 MB of HBM
// writes in r2/r3; the half-selected output is done on VALUES via cndmask).
__global__ __launch_bounds__(256, 2) void attn_kernel(const u16* __restrict__ qb,
    const u16* __restrict__ kb, const u16* __restrict__ vb, u16* __restrict__ cb){
  __shared__ __align__(16) char smem[79872];
  u16* q_lds = (u16*)smem;                 // [128][72]
  u16* k_lds = (u16*)(smem + 18432);       // [128][72]
  float* S   = (float*)smem;               // [128][132] f32, overlays q,k
  u32* wl    = (u32*)(smem + 67584);       // [256][12] packed (bf16 w | idx)
  int sh = blockIdx.x;
  int s = sh >> 3, hh = sh & 7;
  int t = threadIdx.x, lane = t & 63, wave = t >> 6;
  const u16* qg = qb + (size_t)sh * (B_*DK_);
  const u16* kg = kb + (size_t)sh * (B_*DK_);
  const u16* vg = vb + (size_t)sh * (B_*DK_);
  #pragma unroll
  for (int rr=0; rr<4; rr++){
    int idx = rr*2048 + t*8;
    int row = idx >> 6, col = idx & 63;
    *(u32x4*)&q_lds[row*72+col] = *(const u32x4*)&qg[idx];
    *(u32x4*)&k_lds[row*72+col] = *(const u32x4*)&kg[idx];
  }
  __syncthreads();
  int wm = wave>>1, wn = wave&1, rsel = lane & 15;
  f32x4 sacc[4][4] = {};
  #pragma unroll
  for (int ks=0; ks<2; ks++){
    asm volatile("s_nop 7\n\ts_nop 7");
    int ko = ks*32 + (lane>>4)*8;
    u32x4 qf[4], kf[4];
    #pragma unroll
    for (int i=0;i<4;i++){
      qf[i] = *(const u32x4*)&q_lds[(wm*64+i*16+rsel)*72 + ko];
      kf[i] = *(const u32x4*)&k_lds[(wn*64+i*16+rsel)*72 + ko];
    }
    #pragma unroll
    for (int i=0;i<4;i++)
      #pragma unroll
      for (int j=0;j<4;j++)
        mfma16(sacc[i][j], qf[i], kf[j]);
  }
  asm volatile("s_nop 7\n\ts_nop 7");
  __syncthreads();  // MFMA reads of q,k complete before S overlays them
  int rb = (lane>>4)*4;
  #pragma unroll
  for (int i=0;i<4;i++)
    #pragma unroll
    for (int j=0;j<4;j++)
      #pragma unroll
      for (int rg=0;rg<4;rg++)
        S[(wm*64+i*16+rb+rg)*132 + wn*64+j*16+rsel] = sacc[i][j][rg] * 0.125f;
  __syncthreads();
  // ---- per-row top-12 (2 threads/row, 64 elems each), vectorized reads ----
  int r = t >> 1, half = t & 1;
  const f32x4* srow4 = (const f32x4*)(S + r*132 + half*64);
  float kv[12];
  #pragma unroll
  for (int i=0;i<12;i++) kv[i] = -3.4e38f;
  for (int i4=0;i4<16;i4++){
    f32x4 v4 = srow4[i4];
    float m4 = fmaxf(fmaxf(v4[0],v4[1]), fmaxf(v4[2],v4[3]));
    if (m4 > kv[11]){
      #pragma unroll
      for (int z=0; z<4; z++){
        float inc = v4[z];
        if (inc > kv[11]){
          #pragma unroll
          for (int p=0;p<12;p++){
            float cur = kv[p];
            bool gt = inc > cur;
            kv[p] = gt ? inc : cur;
            inc   = gt ? cur : inc;
          }
        }
      }
    }
  }
  // merge two sorted-desc 12-lists: kth = min_i max(a[i], b[11-i])
  float kth = 3.4e38f;
  #pragma unroll
  for (int i=0;i<12;i++){
    float pb = __shfl_xor(kv[11-i], 1);
    kth = fminf(kth, fmaxf(kv[i], pb));
  }
  float mx = fmaxf(kv[0], __shfl_xor(kv[0], 1));
  // ---- exp + compact winners ----
  float sum = 0.f;
  int n = 0;
  u32* myw = wl + t*12;
  for (int i4=0;i4<16;i4++){
    f32x4 v4 = srow4[i4];
    #pragma unroll
    for (int z=0; z<4; z++){
      float v = v4[z];
      if (v >= kth && n < 12){
        float e = __expf(v - mx);
        sum += e;
        myw[n] = ((u32)f2bf(e) << 16) | (u32)(half*64 + i4*4 + z);
        n++;
      }
    }
  }
  float tsum = sum + __shfl_xor(sum, 1);
  // ---- sparse PV: ctx[r] = sum_w w * V[c] ---- (facc static-indexed only)
  float facc[64];
  #pragma unroll
  for (int d=0; d<64; d++) facc[d] = 0.f;
  for (int j=0; j<n; j++){
    u32 e = myw[j];
    float w = __builtin_bit_cast(float, e & 0xffff0000u);
    const u32x4* vr = (const u32x4*)(vg + (size_t)(e & 0xffffu)*DK_);
    #pragma unroll
    for (int q8=0;q8<8;q8++){
      u32x4 u = vr[q8];
      #pragma unroll
      for (int z=0;z<4;z++){
        float lo = __builtin_bit_cast(float, u[z] << 16);
        float hi = __builtin_bit_cast(float, u[z] & 0xffff0000u);
        facc[q8*8+z*2]   = fmaf(w, lo, facc[q8*8+z*2]);
        facc[q8*8+z*2+1] = fmaf(w, hi, facc[q8*8+z*2+1]);
      }
    }
  }
  // ---- partner reduce + half-select on VALUES (static indices) + store ----
  float inv = 1.f / tsum;
  u16* orow = cb + ((size_t)(s*B_ + r))*D_ + hh*DK_ + half*32;
  #pragma unroll
  for (int q4=0; q4<4; q4++){
    u32x4 pkk;
    #pragma unroll
    for (int z=0; z<2; z++){
      int d = q4*8 + z*4;
      float lo0 = facc[d]      + __shfl_xor(facc[d],      1);
      float lo1 = facc[d+1]    + __shfl_xor(facc[d+1],    1);
      float lo2 = facc[d+2]    + __shfl_xor(facc[d+2],    1);
      float lo3 = facc[d+3]    + __shfl_xor(facc[d+3],    1);
      float hi0 = facc[32+d]   + __shfl_xor(facc[32+d],   1);
      float hi1 = facc[32+d+1] + __shfl_xor(facc[32+d+1], 1);
      float hi2 = facc[32+d+2] + __shfl_xor(facc[32+d+2], 1);
      float hi3 = facc[32+d+3] + __shfl_xor(facc[32+d+3], 1);
      float o0 = (half ? hi0 : lo0) * inv;
      float o1 = (half ? hi1 : lo1) * inv;
      float o2 = (half ? hi2 : lo2) * inv;
      float o3 = (half ? hi3 : lo3) * inv;
      pkk[z*2]   = (u32)f2bf(o0) | ((u32)f2bf(o1) << 16);
      pkk[z*2+1] = (u32)f2bf(o2) | ((u32)f2bf(o3) << 16);
    }
    *(u32x4*)(orow + q4*8) = pkk;
  }
}

extern "C" void kernel_launch(void* const* d_in, const int* in_sizes, int n_in,
                              void* d_out, int out_size, void* d_ws, size_t ws_size,
                              hipStream_t stream) {
  const float* x    = (const float*)d_in[0];
  const float* Win  = (const float*)d_in[1];
  const float* bin  = (const float*)d_in[2];
  const float* ln1g = (const float*)d_in[3];
  const float* ln1b = (const float*)d_in[4];
  const float* Wq   = (const float*)d_in[5];
  const float* Wk   = (const float*)d_in[6];
  const float* Wv   = (const float*)d_in[7];
  const float* Wo   = (const float*)d_in[8];
  const float* bo   = (const float*)d_in[9];
  const float* ln2g = (const float*)d_in[10];
  const float* ln2b = (const float*)d_in[11];
  const float* W1   = (const float*)d_in[12];
  const float* b1   = (const float*)d_in[13];
  const float* W2   = (const float*)d_in[14];
  const float* b2   = (const float*)d_in[15];
  const float* lnfg = (const float*)d_in[16];
  const float* lnfb = (const float*)d_in[17];

  char* ws = (char*)d_ws;
  float* h  = (float*)(ws);                      // 134217728 B
  u16* yb   = (u16*)(ws + 134217728ull);         // 67108864 B
  u16* qb   = (u16*)(ws + 201326592ull);         // q,k,v contiguous
  u16* kb   = (u16*)(ws + 268435456ull);
  u16* vb   = (u16*)(ws + 335544320ull);
  u16* cb   = (u16*)(ws + 402653184ull);
  u16* act  = qb;                                // overlays qb..cb
  u16* wqkvT= (u16*)(ws + 469762048ull);         // [L][3][D][D] = 6 MB
  u16* woT  = (u16*)(ws + 476053504ull);         // [L][D][D] = 2 MB
  u16* w1T  = (u16*)(ws + 478150656ull);         // 8 MB
  u16* w2T  = (u16*)(ws + 486539264ull);         // 8 MB
  float* pe = (float*)(ws + 494927872ull);       // 1 MB

  dim3 tb(32,8);
  pe_kernel<<<S_, D_, 0, stream>>>(pe);
  transpose_bf16<<<dim3(D_/32, D_/32, L_), tb, 0, stream>>>(Wq, wqkvT,            D_, D_, (size_t)3*D_*D_);
  transpose_bf16<<<dim3(D_/32, D_/32, L_), tb, 0, stream>>>(Wk, wqkvT + D_*D_,    D_, D_, (size_t)3*D_*D_);
  transpose_bf16<<<dim3(D_/32, D_/32, L_), tb, 0, stream>>>(Wv, wqkvT + 2*D_*D_,  D_, D_, (size_t)3*D_*D_);
  transpose_bf16<<<dim3(D_/32, D_/32, L_), tb, 0, stream>>>(Wo, woT,              D_, D_, (size_t)D_*D_);
  transpose_bf16<<<dim3(F_/32, D_/32, L_), tb, 0, stream>>>(W1, w1T, D_, F_, (size_t)D_*F_);
  transpose_bf16<<<dim3(D_/32, F_/32, L_), tb, 0, stream>>>(W2, w2T, F_, D_, (size_t)F_*D_);
  inproj_kernel<<<SB_, D_, 0, stream>>>(x, Win, bin, pe, h);

  for (int l=0; l<L_; l++){
    ln_kernel<0><<<SB_/4, 256, 0, stream>>>(h, ln1g + l*D_, ln1b + l*D_, yb, nullptr);
    gemm_kernel<0><<<dim3(12,512), 256, 0, stream>>>(yb, wqkvT + (size_t)l*3*D_*D_, nullptr, nullptr, qb, 1536, D_);
    attn_kernel<<<S_*H_, 256, 0, stream>>>(qb, kb, vb, cb);
    gemm_kernel<1><<<dim3(4,512), 256, 0, stream>>>(cb, woT + (size_t)l*D_*D_, bo + l*D_, h, nullptr, D_, D_);
    ln_kernel<0><<<SB_/4, 256, 0, stream>>>(h, ln2g + l*D_, ln2b + l*D_, yb, nullptr);
    gemm_kernel<2><<<dim3(16,512), 256, 0, stream>>>(yb, w1T + (size_t)l*D_*F_, b1 + l*F_, nullptr, act, F_, D_);
    gemm_kernel<1><<<dim3(4,512), 256, 0, stream>>>(act, w2T + (size_t)l*F_*D_, b2 + l*D_, h, nullptr, D_, F_);
  }
  ln_kernel<1><<<SB_/4, 256, 0, stream>>>(h, lnfg, lnfb, nullptr, (float*)d_out);
}

// Round 5
// 3858.207 us; speedup vs baseline: 1.5739x; 1.0533x over previous
//
#include <hip/hip_runtime.h>
#include <math.h>

#define S_ 512
#define B_ 128
#define D_ 512
#define I_ 64
#define F_ 2048
#define H_ 8
#define DK_ 64
#define L_ 4
#define SB_ (S_*B_)

typedef unsigned short u16;
typedef unsigned int u32;
typedef __attribute__((ext_vector_type(4))) unsigned int u32x4;
typedef __attribute__((ext_vector_type(4))) float f32x4;

__device__ __forceinline__ u16 f2bf(float f){
  u32 x = __builtin_bit_cast(u32, f);
  x += 0x7fffu + ((x >> 16) & 1u);
  return (u16)(x >> 16);
}

__device__ __forceinline__ void mfma16(f32x4& c, const u32x4& a, const u32x4& b){
  asm volatile("v_mfma_f32_16x16x32_bf16 %0, %1, %2, %0" : "+v"(c) : "v"(a), "v"(b));
}

// async global->LDS, 16 B per lane (m97 pattern)
__device__ __forceinline__ void gload16(const u16* g, u16* l){
  __builtin_amdgcn_global_load_lds((const __attribute__((address_space(1))) unsigned int*)g,
                                   (__attribute__((address_space(3))) unsigned int*)l, 16, 0, 0);
}

// ---------------- positional encoding table ----------------
__global__ void pe_kernel(float* __restrict__ pe){
  int s = blockIdx.x, d = threadIdx.x;
  float e = expf((float)(d & ~1) * (-9.210340371976184f / (float)D_));
  float arg = (float)s * e;
  pe[s*D_ + d] = (d & 1) ? cosf(arg) : sinf(arg);
}

// ---------------- weight transpose + fp32->bf16 ----------------
__global__ void transpose_bf16(const float* __restrict__ src, u16* __restrict__ dst,
                               int R, int C, size_t zstride){
  __shared__ float t[32][33];
  size_t sbase = (size_t)blockIdx.z * R * C;
  size_t dbase = (size_t)blockIdx.z * zstride;
  int r0 = blockIdx.y*32, c0 = blockIdx.x*32;
  int tx = threadIdx.x, ty = threadIdx.y;
  #pragma unroll
  for (int j=0;j<4;j++)
    t[ty+j*8][tx] = src[sbase + (size_t)(r0+ty+j*8)*C + c0+tx];
  __syncthreads();
  #pragma unroll
  for (int j=0;j<4;j++)
    dst[dbase + (size_t)(c0+ty+j*8)*R + r0+tx] = f2bf(t[tx][ty+j*8]);
}

// ---------------- input projection + scale + PE ----------------
// r4 fix: naive version made 65536 blocks re-read Win from L2 (8.6 TB of L2
// traffic -> 330 us). Now: 512 blocks x 128 rows; Win column (64 f32) lives
// in REGISTERS per thread (loaded coalesced once), x rows staged 8-at-a-time
// in LDS (broadcast reads). All register arrays statically indexed (rule #20).
__global__ __launch_bounds__(512) void inproj_kernel(const float* __restrict__ x,
    const float* __restrict__ Win, const float* __restrict__ bin,
    const float* __restrict__ pe, float* __restrict__ h){
  __shared__ float xs[8][64];
  int t = threadIdx.x;           // = output column d
  float w[64];
  #pragma unroll
  for (int i=0;i<64;i++) w[i] = Win[i*D_ + t];
  float bd = bin[t];
  int r0 = blockIdx.x * 128;
  for (int batch=0; batch<16; batch++){
    int rb = r0 + batch*8;
    {
      int rr = t >> 6, i = t & 63;
      int r = rb + rr;
      int s = r >> 7, b = r & 127;
      xs[rr][i] = x[((size_t)b*S_ + s)*I_ + i];
    }
    __syncthreads();
    float acc[8];
    #pragma unroll
    for (int rr=0;rr<8;rr++) acc[rr] = 0.f;
    #pragma unroll
    for (int i4=0;i4<16;i4++){
      f32x4 xv[8];
      #pragma unroll
      for (int rr=0;rr<8;rr++) xv[rr] = *(const f32x4*)&xs[rr][i4*4];
      #pragma unroll
      for (int rr=0;rr<8;rr++){
        acc[rr] = fmaf(xv[rr][0], w[i4*4+0], acc[rr]);
        acc[rr] = fmaf(xv[rr][1], w[i4*4+1], acc[rr]);
        acc[rr] = fmaf(xv[rr][2], w[i4*4+2], acc[rr]);
        acc[rr] = fmaf(xv[rr][3], w[i4*4+3], acc[rr]);
      }
    }
    #pragma unroll
    for (int rr=0;rr<8;rr++){
      int r = rb + rr;
      int s = r >> 7;
      h[(size_t)r*D_ + t] = (acc[rr] + bd) * 22.627416997969522f + pe[s*D_ + t];
    }
    __syncthreads();
  }
}

// ---------------- LayerNorm ----------------
template<int FINAL>
__global__ __launch_bounds__(256) void ln_kernel(const float* __restrict__ hsrc,
    const float* __restrict__ g, const float* __restrict__ bb,
    u16* __restrict__ outb, float* __restrict__ outf){
  int row = blockIdx.x*4 + (threadIdx.x>>6);
  int lane = threadIdx.x & 63;
  const float* hr = hsrc + (size_t)row*D_ + lane*8;
  f32x4 a0 = *(const f32x4*)hr;
  f32x4 a1 = *(const f32x4*)(hr+4);
  float v[8];
  #pragma unroll
  for (int j=0;j<4;j++){ v[j]=a0[j]; v[4+j]=a1[j]; }
  float sum = 0.f;
  #pragma unroll
  for (int j=0;j<8;j++) sum += v[j];
  #pragma unroll
  for (int m=1;m<64;m<<=1) sum += __shfl_xor(sum, m);
  float mean = sum * (1.f/(float)D_);
  float s2 = 0.f;
  #pragma unroll
  for (int j=0;j<8;j++){ float dd = v[j]-mean; s2 = fmaf(dd,dd,s2); }
  #pragma unroll
  for (int m=1;m<64;m<<=1) s2 += __shfl_xor(s2, m);
  float inv = rsqrtf(s2*(1.f/(float)D_) + 1e-5f);
  f32x4 g0 = *(const f32x4*)&g[lane*8];
  f32x4 g1 = *(const f32x4*)&g[lane*8+4];
  f32x4 b0 = *(const f32x4*)&bb[lane*8];
  f32x4 b1 = *(const f32x4*)&bb[lane*8+4];
  float o[8];
  #pragma unroll
  for (int j=0;j<4;j++){
    o[j]   = (v[j]-mean)*inv*g0[j] + b0[j];
    o[4+j] = (v[4+j]-mean)*inv*g1[j] + b1[j];
  }
  if (FINAL == 0){
    u32x4 pk;
    #pragma unroll
    for (int j=0;j<4;j++)
      pk[j] = (u32)f2bf(o[2*j]) | ((u32)f2bf(o[2*j+1])<<16);
    *(u32x4*)&outb[(size_t)row*D_ + lane*8] = pk;
  } else {
    int s = row>>7, b = row&(B_-1);
    float* op = outf + ((size_t)b*S_ + s)*D_ + lane*8;
    f32x4 r0, r1;
    #pragma unroll
    for (int j=0;j<4;j++){ r0[j]=o[j]; r1[j]=o[4+j]; }
    *(f32x4*)op = r0;
    *(f32x4*)(op+4) = r1;
  }
}

// ---------------- bf16 MFMA GEMM, 128x128 tile, global_load_lds (m97) ----------------
// Grid: (n_tiles, m_tiles) — n fastest so consecutive blocks share the A panel
// (L2 hits); XCD chunk swizzle keeps panel-sharing blocks on one XCD L2.
// MODE 0: QKV fused N=1536; MODE 1: residual += ; MODE 2: gelu->bf16
template<int MODE>
__global__ __launch_bounds__(256) void gemm_kernel(const u16* __restrict__ A,
    const u16* __restrict__ Wt, const float* __restrict__ bias,
    float* __restrict__ hres, u16* __restrict__ outb, int N, int K){
  const u32 nwg = gridDim.x * gridDim.y;
  u32 wg = blockIdx.y * gridDim.x + blockIdx.x;
  wg = (wg & 7) * (nwg >> 3) + (wg >> 3);   // bijective XCD chunk swizzle (nwg%8==0)
  const int m0 = (int)(wg / gridDim.x) * 128;
  const int n0 = (int)(wg % gridDim.x) * 128;
  __shared__ u16 a_lds[128*32];
  __shared__ u16 b_lds[128*32];
  const int t = threadIdx.x;
  const int lane = t & 63, wave = t >> 6;
  const int wm = wave >> 1, wn = wave & 1;
  const int rsel = lane & 15, kg = (lane>>4)*8;
  const u16* ag = A  + (size_t)(m0 + (t>>2))*K + (t&3)*8;
  const u16* bg = Wt + (size_t)(n0 + (t>>2))*K + (t&3)*8;
  f32x4 acc[4][4] = {};
  for (int k0 = 0; k0 < K; k0 += 32){
    asm volatile("s_nop 7\n\ts_nop 7"); // WAR insurance before LDS overwrite
    __syncthreads();
    gload16(ag + k0,                &a_lds[t*8]);
    gload16(ag + 64*(size_t)K + k0, &a_lds[2048 + t*8]);
    gload16(bg + k0,                &b_lds[t*8]);
    gload16(bg + 64*(size_t)K + k0, &b_lds[2048 + t*8]);
    __syncthreads();
    u32x4 af[4], bfr[4];
    #pragma unroll
    for (int i=0;i<4;i++){
      af[i]  = *(const u32x4*)&a_lds[(wm*64 + i*16 + rsel)*32 + kg];
      bfr[i] = *(const u32x4*)&b_lds[(wn*64 + i*16 + rsel)*32 + kg];
    }
    #pragma unroll
    for (int i=0;i<4;i++)
      #pragma unroll
      for (int j=0;j<4;j++)
        mfma16(acc[i][j], af[i], bfr[j]);
  }
  asm volatile("s_nop 7\n\ts_nop 7");
  const int rb = (lane>>4)*4;
  #pragma unroll
  for (int i=0;i<4;i++){
    #pragma unroll
    for (int j=0;j<4;j++){
      int gn = n0 + wn*64 + j*16 + rsel;
      #pragma unroll
      for (int rg=0;rg<4;rg++){
        int gr = m0 + wm*64 + i*16 + rb + rg;
        float val = acc[i][j][rg];
        if (MODE == 0){
          int mat = gn >> 9;
          int hh = (gn >> 6) & 7, dd = gn & 63;
          int s = gr >> 7, b = gr & 127;
          u16* dst = outb + (size_t)mat*33554432ull;
          dst[(size_t)((s*H_ + hh)*B_ + b)*DK_ + dd] = f2bf(val);
        } else if (MODE == 1){
          hres[(size_t)gr*D_ + gn] += val + bias[gn];
        } else {
          float xg = val + bias[gn];
          float ge = 0.5f*xg*(1.f + erff(xg*0.7071067811865476f));
          outb[(size_t)gr*(size_t)N + gn] = f2bf(ge);
        }
      }
    }
  }
}

// ---------------- fused batch-attention per (s, head) ----------------
// 78 KB LDS -> 2 blocks/CU. ALL accumulator arrays statically indexed
// (rule #20: runtime-indexed VGPR arrays go to scratch -> 480 MB of HBM
// writes in r2/r3; the half-selected output is done on VALUES via cndmask).
__global__ __launch_bounds__(256, 2) void attn_kernel(const u16* __restrict__ qb,
    const u16* __restrict__ kb, const u16* __restrict__ vb, u16* __restrict__ cb){
  __shared__ __align__(16) char smem[79872];
  u16* q_lds = (u16*)smem;                 // [128][72]
  u16* k_lds = (u16*)(smem + 18432);       // [128][72]
  float* S   = (float*)smem;               // [128][132] f32, overlays q,k
  u32* wl    = (u32*)(smem + 67584);       // [256][12] packed (bf16 w | idx)
  int sh = blockIdx.x;
  int s = sh >> 3, hh = sh & 7;
  int t = threadIdx.x, lane = t & 63, wave = t >> 6;
  const u16* qg = qb + (size_t)sh * (B_*DK_);
  const u16* kg = kb + (size_t)sh * (B_*DK_);
  const u16* vg = vb + (size_t)sh * (B_*DK_);
  #pragma unroll
  for (int rr=0; rr<4; rr++){
    int idx = rr*2048 + t*8;
    int row = idx >> 6, col = idx & 63;
    *(u32x4*)&q_lds[row*72+col] = *(const u32x4*)&qg[idx];
    *(u32x4*)&k_lds[row*72+col] = *(const u32x4*)&kg[idx];
  }
  __syncthreads();
  int wm = wave>>1, wn = wave&1, rsel = lane & 15;
  f32x4 sacc[4][4] = {};
  #pragma unroll
  for (int ks=0; ks<2; ks++){
    asm volatile("s_nop 7\n\ts_nop 7");
    int ko = ks*32 + (lane>>4)*8;
    u32x4 qf[4], kf[4];
    #pragma unroll
    for (int i=0;i<4;i++){
      qf[i] = *(const u32x4*)&q_lds[(wm*64+i*16+rsel)*72 + ko];
      kf[i] = *(const u32x4*)&k_lds[(wn*64+i*16+rsel)*72 + ko];
    }
    #pragma unroll
    for (int i=0;i<4;i++)
      #pragma unroll
      for (int j=0;j<4;j++)
        mfma16(sacc[i][j], qf[i], kf[j]);
  }
  asm volatile("s_nop 7\n\ts_nop 7");
  __syncthreads();  // MFMA reads of q,k complete before S overlays them
  int rb = (lane>>4)*4;
  #pragma unroll
  for (int i=0;i<4;i++)
    #pragma unroll
    for (int j=0;j<4;j++)
      #pragma unroll
      for (int rg=0;rg<4;rg++)
        S[(wm*64+i*16+rb+rg)*132 + wn*64+j*16+rsel] = sacc[i][j][rg] * 0.125f;
  __syncthreads();
  // ---- per-row top-12 (2 threads/row, 64 elems each), vectorized reads ----
  int r = t >> 1, half = t & 1;
  const f32x4* srow4 = (const f32x4*)(S + r*132 + half*64);
  float kv[12];
  #pragma unroll
  for (int i=0;i<12;i++) kv[i] = -3.4e38f;
  for (int i4=0;i4<16;i4++){
    f32x4 v4 = srow4[i4];
    float m4 = fmaxf(fmaxf(v4[0],v4[1]), fmaxf(v4[2],v4[3]));
    if (m4 > kv[11]){
      #pragma unroll
      for (int z=0; z<4; z++){
        float inc = v4[z];
        if (inc > kv[11]){
          #pragma unroll
          for (int p=0;p<12;p++){
            float cur = kv[p];
            bool gt = inc > cur;
            kv[p] = gt ? inc : cur;
            inc   = gt ? cur : inc;
          }
        }
      }
    }
  }
  // merge two sorted-desc 12-lists: kth = min_i max(a[i], b[11-i])
  float kth = 3.4e38f;
  #pragma unroll
  for (int i=0;i<12;i++){
    float pb = __shfl_xor(kv[11-i], 1);
    kth = fminf(kth, fmaxf(kv[i], pb));
  }
  float mx = fmaxf(kv[0], __shfl_xor(kv[0], 1));
  // ---- exp + compact winners ----
  float sum = 0.f;
  int n = 0;
  u32* myw = wl + t*12;
  for (int i4=0;i4<16;i4++){
    f32x4 v4 = srow4[i4];
    #pragma unroll
    for (int z=0; z<4; z++){
      float v = v4[z];
      if (v >= kth && n < 12){
        float e = __expf(v - mx);
        sum += e;
        myw[n] = ((u32)f2bf(e) << 16) | (u32)(half*64 + i4*4 + z);
        n++;
      }
    }
  }
  float tsum = sum + __shfl_xor(sum, 1);
  // ---- sparse PV: ctx[r] = sum_w w * V[c] ---- (facc static-indexed only)
  float facc[64];
  #pragma unroll
  for (int d=0; d<64; d++) facc[d] = 0.f;
  for (int j=0; j<n; j++){
    u32 e = myw[j];
    float w = __builtin_bit_cast(float, e & 0xffff0000u);
    const u32x4* vr = (const u32x4*)(vg + (size_t)(e & 0xffffu)*DK_);
    #pragma unroll
    for (int q8=0;q8<8;q8++){
      u32x4 u = vr[q8];
      #pragma unroll
      for (int z=0;z<4;z++){
        float lo = __builtin_bit_cast(float, u[z] << 16);
        float hi = __builtin_bit_cast(float, u[z] & 0xffff0000u);
        facc[q8*8+z*2]   = fmaf(w, lo, facc[q8*8+z*2]);
        facc[q8*8+z*2+1] = fmaf(w, hi, facc[q8*8+z*2+1]);
      }
    }
  }
  // ---- partner reduce + half-select on VALUES (static indices) + store ----
  float inv = 1.f / tsum;
  u16* orow = cb + ((size_t)(s*B_ + r))*D_ + hh*DK_ + half*32;
  #pragma unroll
  for (int q4=0; q4<4; q4++){
    u32x4 pkk;
    #pragma unroll
    for (int z=0; z<2; z++){
      int d = q4*8 + z*4;
      float lo0 = facc[d]      + __shfl_xor(facc[d],      1);
      float lo1 = facc[d+1]    + __shfl_xor(facc[d+1],    1);
      float lo2 = facc[d+2]    + __shfl_xor(facc[d+2],    1);
      float lo3 = facc[d+3]    + __shfl_xor(facc[d+3],    1);
      float hi0 = facc[32+d]   + __shfl_xor(facc[32+d],   1);
      float hi1 = facc[32+d+1] + __shfl_xor(facc[32+d+1], 1);
      float hi2 = facc[32+d+2] + __shfl_xor(facc[32+d+2], 1);
      float hi3 = facc[32+d+3] + __shfl_xor(facc[32+d+3], 1);
      float o0 = (half ? hi0 : lo0) * inv;
      float o1 = (half ? hi1 : lo1) * inv;
      float o2 = (half ? hi2 : lo2) * inv;
      float o3 = (half ? hi3 : lo3) * inv;
      pkk[z*2]   = (u32)f2bf(o0) | ((u32)f2bf(o1) << 16);
      pkk[z*2+1] = (u32)f2bf(o2) | ((u32)f2bf(o3) << 16);
    }
    *(u32x4*)(orow + q4*8) = pkk;
  }
}

extern "C" void kernel_launch(void* const* d_in, const int* in_sizes, int n_in,
                              void* d_out, int out_size, void* d_ws, size_t ws_size,
                              hipStream_t stream) {
  const float* x    = (const float*)d_in[0];
  const float* Win  = (const float*)d_in[1];
  const float* bin  = (const float*)d_in[2];
  const float* ln1g = (const float*)d_in[3];
  const float* ln1b = (const float*)d_in[4];
  const float* Wq   = (const float*)d_in[5];
  const float* Wk   = (const float*)d_in[6];
  const float* Wv   = (const float*)d_in[7];
  const float* Wo   = (const float*)d_in[8];
  const float* bo   = (const float*)d_in[9];
  const float* ln2g = (const float*)d_in[10];
  const float* ln2b = (const float*)d_in[11];
  const float* W1   = (const float*)d_in[12];
  const float* b1   = (const float*)d_in[13];
  const float* W2   = (const float*)d_in[14];
  const float* b2   = (const float*)d_in[15];
  const float* lnfg = (const float*)d_in[16];
  const float* lnfb = (const float*)d_in[17];

  char* ws = (char*)d_ws;
  float* h  = (float*)(ws);                      // 134217728 B
  u16* yb   = (u16*)(ws + 134217728ull);         // 67108864 B
  u16* qb   = (u16*)(ws + 201326592ull);         // q,k,v contiguous
  u16* kb   = (u16*)(ws + 268435456ull);
  u16* vb   = (u16*)(ws + 335544320ull);
  u16* cb   = (u16*)(ws + 402653184ull);
  u16* act  = qb;                                // overlays qb..cb
  u16* wqkvT= (u16*)(ws + 469762048ull);         // [L][3][D][D] = 6 MB
  u16* woT  = (u16*)(ws + 476053504ull);         // [L][D][D] = 2 MB
  u16* w1T  = (u16*)(ws + 478150656ull);         // 8 MB
  u16* w2T  = (u16*)(ws + 486539264ull);         // 8 MB
  float* pe = (float*)(ws + 494927872ull);       // 1 MB

  dim3 tb(32,8);
  pe_kernel<<<S_, D_, 0, stream>>>(pe);
  transpose_bf16<<<dim3(D_/32, D_/32, L_), tb, 0, stream>>>(Wq, wqkvT,            D_, D_, (size_t)3*D_*D_);
  transpose_bf16<<<dim3(D_/32, D_/32, L_), tb, 0, stream>>>(Wk, wqkvT + D_*D_,    D_, D_, (size_t)3*D_*D_);
  transpose_bf16<<<dim3(D_/32, D_/32, L_), tb, 0, stream>>>(Wv, wqkvT + 2*D_*D_,  D_, D_, (size_t)3*D_*D_);
  transpose_bf16<<<dim3(D_/32, D_/32, L_), tb, 0, stream>>>(Wo, woT,              D_, D_, (size_t)D_*D_);
  transpose_bf16<<<dim3(F_/32, D_/32, L_), tb, 0, stream>>>(W1, w1T, D_, F_, (size_t)D_*F_);
  transpose_bf16<<<dim3(D_/32, F_/32, L_), tb, 0, stream>>>(W2, w2T, F_, D_, (size_t)F_*D_);
  inproj_kernel<<<512, 512, 0, stream>>>(x, Win, bin, pe, h);

  for (int l=0; l<L_; l++){
    ln_kernel<0><<<SB_/4, 256, 0, stream>>>(h, ln1g + l*D_, ln1b + l*D_, yb, nullptr);
    gemm_kernel<0><<<dim3(12,512), 256, 0, stream>>>(yb, wqkvT + (size_t)l*3*D_*D_, nullptr, nullptr, qb, 1536, D_);
    attn_kernel<<<S_*H_, 256, 0, stream>>>(qb, kb, vb, cb);
    gemm_kernel<1><<<dim3(4,512), 256, 0, stream>>>(cb, woT + (size_t)l*D_*D_, bo + l*D_, h, nullptr, D_, D_);
    ln_kernel<0><<<SB_/4, 256, 0, stream>>>(h, ln2g + l*D_, ln2b + l*D_, yb, nullptr);
    gemm_kernel<2><<<dim3(16,512), 256, 0, stream>>>(yb, w1T + (size_t)l*D_*F_, b1 + l*F_, nullptr, act, F_, D_);
    gemm_kernel<1><<<dim3(4,512), 256, 0, stream>>>(act, w2T + (size_t)l*F_*D_, b2 + l*D_, h, nullptr, D_, F_);
  }
  ln_kernel<1><<<SB_/4, 256, 0, stream>>>(h, lnfg, lnfb, nullptr, (float*)d_out);
}

// Round 6
// 3663.999 us; speedup vs baseline: 1.6573x; 1.0530x over previous
//
#include <hip/hip_runtime.h>
#include <math.h>

#define S_ 512
#define B_ 128
#define D_ 512
#define I_ 64
#define F_ 2048
#define H_ 8
#define DK_ 64
#define L_ 4
#define SB_ (S_*B_)

typedef unsigned short u16;
typedef unsigned int u32;
typedef __attribute__((ext_vector_type(4))) unsigned int u32x4;
typedef __attribute__((ext_vector_type(4))) float f32x4;

__device__ __forceinline__ u16 f2bf(float f){
  u32 x = __builtin_bit_cast(u32, f);
  x += 0x7fffu + ((x >> 16) & 1u);
  return (u16)(x >> 16);
}

__device__ __forceinline__ void mfma16(f32x4& c, const u32x4& a, const u32x4& b){
  asm volatile("v_mfma_f32_16x16x32_bf16 %0, %1, %2, %0" : "+v"(c) : "v"(a), "v"(b));
}

// async global->LDS, 16 B per lane (m97 pattern)
__device__ __forceinline__ void gload16(const u16* g, u16* l){
  __builtin_amdgcn_global_load_lds((const __attribute__((address_space(1))) unsigned int*)g,
                                   (__attribute__((address_space(3))) unsigned int*)l, 16, 0, 0);
}

// ---------------- positional encoding table ----------------
__global__ void pe_kernel(float* __restrict__ pe){
  int s = blockIdx.x, d = threadIdx.x;
  float e = expf((float)(d & ~1) * (-9.210340371976184f / (float)D_));
  float arg = (float)s * e;
  pe[s*D_ + d] = (d & 1) ? cosf(arg) : sinf(arg);
}

// ---------------- weight transpose + fp32->bf16 ----------------
__global__ void transpose_bf16(const float* __restrict__ src, u16* __restrict__ dst,
                               int R, int C, size_t zstride){
  __shared__ float t[32][33];
  size_t sbase = (size_t)blockIdx.z * R * C;
  size_t dbase = (size_t)blockIdx.z * zstride;
  int r0 = blockIdx.y*32, c0 = blockIdx.x*32;
  int tx = threadIdx.x, ty = threadIdx.y;
  #pragma unroll
  for (int j=0;j<4;j++)
    t[ty+j*8][tx] = src[sbase + (size_t)(r0+ty+j*8)*C + c0+tx];
  __syncthreads();
  #pragma unroll
  for (int j=0;j<4;j++)
    dst[dbase + (size_t)(c0+ty+j*8)*R + r0+tx] = f2bf(t[tx][ty+j*8]);
}

// ---------------- input projection + scale + PE ----------------
// r4 fix: Win column in registers per thread; x rows staged in LDS (L2 traffic
// 8.6 TB -> 64 MB). All register arrays statically indexed (rule #20).
__global__ __launch_bounds__(512) void inproj_kernel(const float* __restrict__ x,
    const float* __restrict__ Win, const float* __restrict__ bin,
    const float* __restrict__ pe, float* __restrict__ h){
  __shared__ float xs[8][64];
  int t = threadIdx.x;           // = output column d
  float w[64];
  #pragma unroll
  for (int i=0;i<64;i++) w[i] = Win[i*D_ + t];
  float bd = bin[t];
  int r0 = blockIdx.x * 128;
  for (int batch=0; batch<16; batch++){
    int rb = r0 + batch*8;
    {
      int rr = t >> 6, i = t & 63;
      int r = rb + rr;
      int s = r >> 7, b = r & 127;
      xs[rr][i] = x[((size_t)b*S_ + s)*I_ + i];
    }
    __syncthreads();
    float acc[8];
    #pragma unroll
    for (int rr=0;rr<8;rr++) acc[rr] = 0.f;
    #pragma unroll
    for (int i4=0;i4<16;i4++){
      f32x4 xv[8];
      #pragma unroll
      for (int rr=0;rr<8;rr++) xv[rr] = *(const f32x4*)&xs[rr][i4*4];
      #pragma unroll
      for (int rr=0;rr<8;rr++){
        acc[rr] = fmaf(xv[rr][0], w[i4*4+0], acc[rr]);
        acc[rr] = fmaf(xv[rr][1], w[i4*4+1], acc[rr]);
        acc[rr] = fmaf(xv[rr][2], w[i4*4+2], acc[rr]);
        acc[rr] = fmaf(xv[rr][3], w[i4*4+3], acc[rr]);
      }
    }
    #pragma unroll
    for (int rr=0;rr<8;rr++){
      int r = rb + rr;
      int s = r >> 7;
      h[(size_t)r*D_ + t] = (acc[rr] + bd) * 22.627416997969522f + pe[s*D_ + t];
    }
    __syncthreads();
  }
}

// ---------------- LayerNorm ----------------
template<int FINAL>
__global__ __launch_bounds__(256) void ln_kernel(const float* __restrict__ hsrc,
    const float* __restrict__ g, const float* __restrict__ bb,
    u16* __restrict__ outb, float* __restrict__ outf){
  int row = blockIdx.x*4 + (threadIdx.x>>6);
  int lane = threadIdx.x & 63;
  const float* hr = hsrc + (size_t)row*D_ + lane*8;
  f32x4 a0 = *(const f32x4*)hr;
  f32x4 a1 = *(const f32x4*)(hr+4);
  float v[8];
  #pragma unroll
  for (int j=0;j<4;j++){ v[j]=a0[j]; v[4+j]=a1[j]; }
  float sum = 0.f;
  #pragma unroll
  for (int j=0;j<8;j++) sum += v[j];
  #pragma unroll
  for (int m=1;m<64;m<<=1) sum += __shfl_xor(sum, m);
  float mean = sum * (1.f/(float)D_);
  float s2 = 0.f;
  #pragma unroll
  for (int j=0;j<8;j++){ float dd = v[j]-mean; s2 = fmaf(dd,dd,s2); }
  #pragma unroll
  for (int m=1;m<64;m<<=1) s2 += __shfl_xor(s2, m);
  float inv = rsqrtf(s2*(1.f/(float)D_) + 1e-5f);
  f32x4 g0 = *(const f32x4*)&g[lane*8];
  f32x4 g1 = *(const f32x4*)&g[lane*8+4];
  f32x4 b0 = *(const f32x4*)&bb[lane*8];
  f32x4 b1 = *(const f32x4*)&bb[lane*8+4];
  float o[8];
  #pragma unroll
  for (int j=0;j<4;j++){
    o[j]   = (v[j]-mean)*inv*g0[j] + b0[j];
    o[4+j] = (v[4+j]-mean)*inv*g1[j] + b1[j];
  }
  if (FINAL == 0){
    u32x4 pk;
    #pragma unroll
    for (int j=0;j<4;j++)
      pk[j] = (u32)f2bf(o[2*j]) | ((u32)f2bf(o[2*j+1])<<16);
    *(u32x4*)&outb[(size_t)row*D_ + lane*8] = pk;
  } else {
    int s = row>>7, b = row&(B_-1);
    float* op = outf + ((size_t)b*S_ + s)*D_ + lane*8;
    f32x4 r0, r1;
    #pragma unroll
    for (int j=0;j<4;j++){ r0[j]=o[j]; r1[j]=o[4+j]; }
    *(f32x4*)op = r0;
    *(f32x4*)(op+4) = r1;
  }
}

// ---------------- bf16 MFMA GEMM, 128x128 tile, global_load_lds (m97) ----------------
// Grid: (n_tiles, m_tiles) — n fastest so consecutive blocks share the A panel
// (L2 hits); XCD chunk swizzle keeps panel-sharing blocks on one XCD L2.
// MODE 0: QKV fused N=1536; MODE 1: residual += ; MODE 2: gelu->bf16
template<int MODE>
__global__ __launch_bounds__(256) void gemm_kernel(const u16* __restrict__ A,
    const u16* __restrict__ Wt, const float* __restrict__ bias,
    float* __restrict__ hres, u16* __restrict__ outb, int N, int K){
  const u32 nwg = gridDim.x * gridDim.y;
  u32 wg = blockIdx.y * gridDim.x + blockIdx.x;
  wg = (wg & 7) * (nwg >> 3) + (wg >> 3);   // bijective XCD chunk swizzle (nwg%8==0)
  const int m0 = (int)(wg / gridDim.x) * 128;
  const int n0 = (int)(wg % gridDim.x) * 128;
  __shared__ u16 a_lds[128*32];
  __shared__ u16 b_lds[128*32];
  const int t = threadIdx.x;
  const int lane = t & 63, wave = t >> 6;
  const int wm = wave >> 1, wn = wave & 1;
  const int rsel = lane & 15, kg = (lane>>4)*8;
  const u16* ag = A  + (size_t)(m0 + (t>>2))*K + (t&3)*8;
  const u16* bg = Wt + (size_t)(n0 + (t>>2))*K + (t&3)*8;
  f32x4 acc[4][4] = {};
  for (int k0 = 0; k0 < K; k0 += 32){
    asm volatile("s_nop 7\n\ts_nop 7"); // WAR insurance before LDS overwrite
    __syncthreads();
    gload16(ag + k0,                &a_lds[t*8]);
    gload16(ag + 64*(size_t)K + k0, &a_lds[2048 + t*8]);
    gload16(bg + k0,                &b_lds[t*8]);
    gload16(bg + 64*(size_t)K + k0, &b_lds[2048 + t*8]);
    __syncthreads();
    u32x4 af[4], bfr[4];
    #pragma unroll
    for (int i=0;i<4;i++){
      af[i]  = *(const u32x4*)&a_lds[(wm*64 + i*16 + rsel)*32 + kg];
      bfr[i] = *(const u32x4*)&b_lds[(wn*64 + i*16 + rsel)*32 + kg];
    }
    #pragma unroll
    for (int i=0;i<4;i++)
      #pragma unroll
      for (int j=0;j<4;j++)
        mfma16(acc[i][j], af[i], bfr[j]);
  }
  asm volatile("s_nop 7\n\ts_nop 7");
  const int rb = (lane>>4)*4;
  #pragma unroll
  for (int i=0;i<4;i++){
    #pragma unroll
    for (int j=0;j<4;j++){
      int gn = n0 + wn*64 + j*16 + rsel;
      #pragma unroll
      for (int rg=0;rg<4;rg++){
        int gr = m0 + wm*64 + i*16 + rb + rg;
        float val = acc[i][j][rg];
        if (MODE == 0){
          int mat = gn >> 9;
          int hh = (gn >> 6) & 7, dd = gn & 63;
          int s = gr >> 7, b = gr & 127;
          u16* dst = outb + (size_t)mat*33554432ull;
          dst[(size_t)((s*H_ + hh)*B_ + b)*DK_ + dd] = f2bf(val);
        } else if (MODE == 1){
          hres[(size_t)gr*D_ + gn] += val + bias[gn];
        } else {
          float xg = val + bias[gn];
          float ge = 0.5f*xg*(1.f + erff(xg*0.7071067811865476f));
          outb[(size_t)gr*(size_t)N + gn] = f2bf(ge);
        }
      }
    }
  }
}

// ---------------- fused batch-attention per (s, head) ----------------
// r5: sparse register-gather PV (768 serial FMA + ~96 dependent loads/thread,
// VALU-bound) replaced by MFMA PV: P (bf16, zero+winner-scatter) and V^T
// overlay the dead S region. LDS 80384 B -> still 2 blocks/CU.
__global__ __launch_bounds__(256, 2) void attn_kernel(const u16* __restrict__ qb,
    const u16* __restrict__ kb, const u16* __restrict__ vb, u16* __restrict__ cb){
  __shared__ __align__(16) char smem[80384];
  u16* q_lds = (u16*)smem;                 // [128][72]
  u16* k_lds = (u16*)(smem + 18432);       // [128][72]
  float* S   = (float*)smem;               // [128][132] f32, overlays q,k
  u16* P     = (u16*)smem;                 // [128][136] bf16, overlays dead S
  u16* vT    = (u16*)(smem + 34816);       // [64][136], overlays dead S
  u32* wl    = (u32*)(smem + 67584);       // [256][12] packed (bf16 w | idx)
  float* rs  = (float*)(smem + 79872);     // [128] inverse row sums
  int sh = blockIdx.x;
  int s = sh >> 3, hh = sh & 7;
  int t = threadIdx.x, lane = t & 63, wave = t >> 6;
  const u16* qg = qb + (size_t)sh * (B_*DK_);
  const u16* kg = kb + (size_t)sh * (B_*DK_);
  const u16* vg = vb + (size_t)sh * (B_*DK_);
  #pragma unroll
  for (int rr=0; rr<4; rr++){
    int idx = rr*2048 + t*8;
    int row = idx >> 6, col = idx & 63;
    *(u32x4*)&q_lds[row*72+col] = *(const u32x4*)&qg[idx];
    *(u32x4*)&k_lds[row*72+col] = *(const u32x4*)&kg[idx];
  }
  __syncthreads();
  int wm = wave>>1, wn = wave&1, rsel = lane & 15;
  f32x4 sacc[4][4] = {};
  #pragma unroll
  for (int ks=0; ks<2; ks++){
    asm volatile("s_nop 7\n\ts_nop 7");
    int ko = ks*32 + (lane>>4)*8;
    u32x4 qf[4], kf[4];
    #pragma unroll
    for (int i=0;i<4;i++){
      qf[i] = *(const u32x4*)&q_lds[(wm*64+i*16+rsel)*72 + ko];
      kf[i] = *(const u32x4*)&k_lds[(wn*64+i*16+rsel)*72 + ko];
    }
    #pragma unroll
    for (int i=0;i<4;i++)
      #pragma unroll
      for (int j=0;j<4;j++)
        mfma16(sacc[i][j], qf[i], kf[j]);
  }
  asm volatile("s_nop 7\n\ts_nop 7");
  __syncthreads();  // MFMA reads of q,k complete before S overlays them
  int rb = (lane>>4)*4;
  #pragma unroll
  for (int i=0;i<4;i++)
    #pragma unroll
    for (int j=0;j<4;j++)
      #pragma unroll
      for (int rg=0;rg<4;rg++)
        S[(wm*64+i*16+rb+rg)*132 + wn*64+j*16+rsel] = sacc[i][j][rg] * 0.125f;
  __syncthreads();
  // ---- per-row top-12 (2 threads/row, 64 elems each), vectorized reads ----
  int r = t >> 1, half = t & 1;
  const f32x4* srow4 = (const f32x4*)(S + r*132 + half*64);
  float kv[12];
  #pragma unroll
  for (int i=0;i<12;i++) kv[i] = -3.4e38f;
  for (int i4=0;i4<16;i4++){
    f32x4 v4 = srow4[i4];
    float m4 = fmaxf(fmaxf(v4[0],v4[1]), fmaxf(v4[2],v4[3]));
    if (m4 > kv[11]){
      #pragma unroll
      for (int z=0; z<4; z++){
        float inc = v4[z];
        if (inc > kv[11]){
          #pragma unroll
          for (int p=0;p<12;p++){
            float cur = kv[p];
            bool gt = inc > cur;
            kv[p] = gt ? inc : cur;
            inc   = gt ? cur : inc;
          }
        }
      }
    }
  }
  // merge two sorted-desc 12-lists: kth = min_i max(a[i], b[11-i])
  float kth = 3.4e38f;
  #pragma unroll
  for (int i=0;i<12;i++){
    float pb = __shfl_xor(kv[11-i], 1);
    kth = fminf(kth, fmaxf(kv[i], pb));
  }
  float mx = fmaxf(kv[0], __shfl_xor(kv[0], 1));
  // ---- exp + compact winners into wl (LDS; n is runtime -> rule #20) ----
  float sum = 0.f;
  int n = 0;
  u32* myw = wl + t*12;
  for (int i4=0;i4<16;i4++){
    f32x4 v4 = srow4[i4];
    #pragma unroll
    for (int z=0; z<4; z++){
      float v = v4[z];
      if (v >= kth && n < 12){
        float e = __expf(v - mx);
        sum += e;
        myw[n] = ((u32)f2bf(e) << 16) | (u32)(half*64 + i4*4 + z);
        n++;
      }
    }
  }
  float tsum = sum + __shfl_xor(sum, 1);
  if (!half) rs[r] = 1.f / tsum;
  __syncthreads();           // S fully consumed by all threads
  // ---- zero P + stage V^T (both overlay dead S; disjoint regions) ----
  {
    u32x4 zz = {0u,0u,0u,0u};
    #pragma unroll
    for (int z=0; z<9; z++){
      int idx = z*256 + t;
      if (idx < 2176) ((u32x4*)P)[idx] = zz;
    }
  }
  #pragma unroll
  for (int rr=0; rr<16; rr++){
    int idx2 = (rr*256 + t)*2;
    u32 u = *(const u32*)&vg[idx2];
    int c = idx2 >> 6, d0 = idx2 & 63;
    vT[d0*136 + c]     = (u16)(u & 0xffffu);
    vT[(d0+1)*136 + c] = (u16)(u >> 16);
  }
  __syncthreads();
  // ---- scatter winners into P (each thread: own row, own half's columns) ----
  u16* prow = P + r*136;
  for (int j=0; j<n; j++){
    u32 e = myw[j];
    prow[e & 0xffffu] = (u16)(e >> 16);
  }
  __syncthreads();
  // ---- PV MFMA: ctx[128][64] = P[128][128] @ V[128][64] ----
  f32x4 cacc[4][2] = {};
  #pragma unroll
  for (int ks=0; ks<4; ks++){
    asm volatile("s_nop 7\n\ts_nop 7");
    int ko = ks*32 + (lane>>4)*8;
    u32x4 pf[4], vf[2];
    #pragma unroll
    for (int i=0;i<4;i++) pf[i] = *(const u32x4*)&P[(wm*64+i*16+rsel)*136 + ko];
    #pragma unroll
    for (int j=0;j<2;j++) vf[j] = *(const u32x4*)&vT[(wn*32+j*16+rsel)*136 + ko];
    #pragma unroll
    for (int i=0;i<4;i++)
      #pragma unroll
      for (int j=0;j<2;j++)
        mfma16(cacc[i][j], pf[i], vf[j]);
  }
  asm volatile("s_nop 7\n\ts_nop 7");
  #pragma unroll
  for (int i=0;i<4;i++)
    #pragma unroll
    for (int j=0;j<2;j++)
      #pragma unroll
      for (int rg=0;rg<4;rg++){
        int m = wm*64 + i*16 + rb + rg;
        int nn = wn*32 + j*16 + rsel;
        float val = cacc[i][j][rg] * rs[m];
        cb[((size_t)(s*B_ + m))*D_ + hh*DK_ + nn] = f2bf(val);
      }
}

extern "C" void kernel_launch(void* const* d_in, const int* in_sizes, int n_in,
                              void* d_out, int out_size, void* d_ws, size_t ws_size,
                              hipStream_t stream) {
  const float* x    = (const float*)d_in[0];
  const float* Win  = (const float*)d_in[1];
  const float* bin  = (const float*)d_in[2];
  const float* ln1g = (const float*)d_in[3];
  const float* ln1b = (const float*)d_in[4];
  const float* Wq   = (const float*)d_in[5];
  const float* Wk   = (const float*)d_in[6];
  const float* Wv   = (const float*)d_in[7];
  const float* Wo   = (const float*)d_in[8];
  const float* bo   = (const float*)d_in[9];
  const float* ln2g = (const float*)d_in[10];
  const float* ln2b = (const float*)d_in[11];
  const float* W1   = (const float*)d_in[12];
  const float* b1   = (const float*)d_in[13];
  const float* W2   = (const float*)d_in[14];
  const float* b2   = (const float*)d_in[15];
  const float* lnfg = (const float*)d_in[16];
  const float* lnfb = (const float*)d_in[17];

  char* ws = (char*)d_ws;
  float* h  = (float*)(ws);                      // 134217728 B
  u16* yb   = (u16*)(ws + 134217728ull);         // 67108864 B
  u16* qb   = (u16*)(ws + 201326592ull);         // q,k,v contiguous
  u16* kb   = (u16*)(ws + 268435456ull);
  u16* vb   = (u16*)(ws + 335544320ull);
  u16* cb   = (u16*)(ws + 402653184ull);
  u16* act  = qb;                                // overlays qb..cb
  u16* wqkvT= (u16*)(ws + 469762048ull);         // [L][3][D][D] = 6 MB
  u16* woT  = (u16*)(ws + 476053504ull);         // [L][D][D] = 2 MB
  u16* w1T  = (u16*)(ws + 478150656ull);         // 8 MB
  u16* w2T  = (u16*)(ws + 486539264ull);         // 8 MB
  float* pe = (float*)(ws + 494927872ull);       // 1 MB

  dim3 tb(32,8);
  pe_kernel<<<S_, D_, 0, stream>>>(pe);
  transpose_bf16<<<dim3(D_/32, D_/32, L_), tb, 0, stream>>>(Wq, wqkvT,            D_, D_, (size_t)3*D_*D_);
  transpose_bf16<<<dim3(D_/32, D_/32, L_), tb, 0, stream>>>(Wk, wqkvT + D_*D_,    D_, D_, (size_t)3*D_*D_);
  transpose_bf16<<<dim3(D_/32, D_/32, L_), tb, 0, stream>>>(Wv, wqkvT + 2*D_*D_,  D_, D_, (size_t)3*D_*D_);
  transpose_bf16<<<dim3(D_/32, D_/32, L_), tb, 0, stream>>>(Wo, woT,              D_, D_, (size_t)D_*D_);
  transpose_bf16<<<dim3(F_/32, D_/32, L_), tb, 0, stream>>>(W1, w1T, D_, F_, (size_t)D_*F_);
  transpose_bf16<<<dim3(D_/32, F_/32, L_), tb, 0, stream>>>(W2, w2T, F_, D_, (size_t)F_*D_);
  inproj_kernel<<<512, 512, 0, stream>>>(x, Win, bin, pe, h);

  for (int l=0; l<L_; l++){
    ln_kernel<0><<<SB_/4, 256, 0, stream>>>(h, ln1g + l*D_, ln1b + l*D_, yb, nullptr);
    gemm_kernel<0><<<dim3(12,512), 256, 0, stream>>>(yb, wqkvT + (size_t)l*3*D_*D_, nullptr, nullptr, qb, 1536, D_);
    attn_kernel<<<S_*H_, 256, 0, stream>>>(qb, kb, vb, cb);
    gemm_kernel<1><<<dim3(4,512), 256, 0, stream>>>(cb, woT + (size_t)l*D_*D_, bo + l*D_, h, nullptr, D_, D_);
    ln_kernel<0><<<SB_/4, 256, 0, stream>>>(h, ln2g + l*D_, ln2b + l*D_, yb, nullptr);
    gemm_kernel<2><<<dim3(16,512), 256, 0, stream>>>(yb, w1T + (size_t)l*D_*F_, b1 + l*F_, nullptr, act, F_, D_);
    gemm_kernel<1><<<dim3(4,512), 256, 0, stream>>>(act, w2T + (size_t)l*F_*D_, b2 + l*D_, h, nullptr, D_, F_);
  }
  ln_kernel<1><<<SB_/4, 256, 0, stream>>>(h, lnfg, lnfb, nullptr, (float*)d_out);
}

// Round 7
// 3607.299 us; speedup vs baseline: 1.6834x; 1.0157x over previous
//
#include <hip/hip_runtime.h>
#include <math.h>

#define S_ 512
#define B_ 128
#define D_ 512
#define I_ 64
#define F_ 2048
#define H_ 8
#define DK_ 64
#define L_ 4
#define SB_ (S_*B_)

typedef unsigned short u16;
typedef unsigned int u32;
typedef __attribute__((ext_vector_type(4))) unsigned int u32x4;
typedef __attribute__((ext_vector_type(4))) float f32x4;

__device__ __forceinline__ u16 f2bf(float f){
  u32 x = __builtin_bit_cast(u32, f);
  x += 0x7fffu + ((x >> 16) & 1u);
  return (u16)(x >> 16);
}

__device__ __forceinline__ void mfma16(f32x4& c, const u32x4& a, const u32x4& b){
  asm volatile("v_mfma_f32_16x16x32_bf16 %0, %1, %2, %0" : "+v"(c) : "v"(a), "v"(b));
}

// async global->LDS, 16 B per lane (m97 pattern)
__device__ __forceinline__ void gload16(const u16* g, u16* l){
  __builtin_amdgcn_global_load_lds((const __attribute__((address_space(1))) unsigned int*)g,
                                   (__attribute__((address_space(3))) unsigned int*)l, 16, 0, 0);
}

// ---------------- positional encoding table ----------------
__global__ void pe_kernel(float* __restrict__ pe){
  int s = blockIdx.x, d = threadIdx.x;
  float e = expf((float)(d & ~1) * (-9.210340371976184f / (float)D_));
  float arg = (float)s * e;
  pe[s*D_ + d] = (d & 1) ? cosf(arg) : sinf(arg);
}

// ---------------- weight transpose + fp32->bf16 ----------------
__global__ void transpose_bf16(const float* __restrict__ src, u16* __restrict__ dst,
                               int R, int C, size_t zstride){
  __shared__ float t[32][33];
  size_t sbase = (size_t)blockIdx.z * R * C;
  size_t dbase = (size_t)blockIdx.z * zstride;
  int r0 = blockIdx.y*32, c0 = blockIdx.x*32;
  int tx = threadIdx.x, ty = threadIdx.y;
  #pragma unroll
  for (int j=0;j<4;j++)
    t[ty+j*8][tx] = src[sbase + (size_t)(r0+ty+j*8)*C + c0+tx];
  __syncthreads();
  #pragma unroll
  for (int j=0;j<4;j++)
    dst[dbase + (size_t)(c0+ty+j*8)*R + r0+tx] = f2bf(t[tx][ty+j*8]);
}

// ---------------- input projection + scale + PE ----------------
__global__ __launch_bounds__(512) void inproj_kernel(const float* __restrict__ x,
    const float* __restrict__ Win, const float* __restrict__ bin,
    const float* __restrict__ pe, float* __restrict__ h){
  __shared__ float xs[8][64];
  int t = threadIdx.x;           // = output column d
  float w[64];
  #pragma unroll
  for (int i=0;i<64;i++) w[i] = Win[i*D_ + t];
  float bd = bin[t];
  int r0 = blockIdx.x * 128;
  for (int batch=0; batch<16; batch++){
    int rb = r0 + batch*8;
    {
      int rr = t >> 6, i = t & 63;
      int r = rb + rr;
      int s = r >> 7, b = r & 127;
      xs[rr][i] = x[((size_t)b*S_ + s)*I_ + i];
    }
    __syncthreads();
    float acc[8];
    #pragma unroll
    for (int rr=0;rr<8;rr++) acc[rr] = 0.f;
    #pragma unroll
    for (int i4=0;i4<16;i4++){
      f32x4 xv[8];
      #pragma unroll
      for (int rr=0;rr<8;rr++) xv[rr] = *(const f32x4*)&xs[rr][i4*4];
      #pragma unroll
      for (int rr=0;rr<8;rr++){
        acc[rr] = fmaf(xv[rr][0], w[i4*4+0], acc[rr]);
        acc[rr] = fmaf(xv[rr][1], w[i4*4+1], acc[rr]);
        acc[rr] = fmaf(xv[rr][2], w[i4*4+2], acc[rr]);
        acc[rr] = fmaf(xv[rr][3], w[i4*4+3], acc[rr]);
      }
    }
    #pragma unroll
    for (int rr=0;rr<8;rr++){
      int r = rb + rr;
      int s = r >> 7;
      h[(size_t)r*D_ + t] = (acc[rr] + bd) * 22.627416997969522f + pe[s*D_ + t];
    }
    __syncthreads();
  }
}

// ---------------- LayerNorm ----------------
template<int FINAL>
__global__ __launch_bounds__(256) void ln_kernel(const float* __restrict__ hsrc,
    const float* __restrict__ g, const float* __restrict__ bb,
    u16* __restrict__ outb, float* __restrict__ outf){
  int row = blockIdx.x*4 + (threadIdx.x>>6);
  int lane = threadIdx.x & 63;
  const float* hr = hsrc + (size_t)row*D_ + lane*8;
  f32x4 a0 = *(const f32x4*)hr;
  f32x4 a1 = *(const f32x4*)(hr+4);
  float v[8];
  #pragma unroll
  for (int j=0;j<4;j++){ v[j]=a0[j]; v[4+j]=a1[j]; }
  float sum = 0.f;
  #pragma unroll
  for (int j=0;j<8;j++) sum += v[j];
  #pragma unroll
  for (int m=1;m<64;m<<=1) sum += __shfl_xor(sum, m);
  float mean = sum * (1.f/(float)D_);
  float s2 = 0.f;
  #pragma unroll
  for (int j=0;j<8;j++){ float dd = v[j]-mean; s2 = fmaf(dd,dd,s2); }
  #pragma unroll
  for (int m=1;m<64;m<<=1) s2 += __shfl_xor(s2, m);
  float inv = rsqrtf(s2*(1.f/(float)D_) + 1e-5f);
  f32x4 g0 = *(const f32x4*)&g[lane*8];
  f32x4 g1 = *(const f32x4*)&g[lane*8+4];
  f32x4 b0 = *(const f32x4*)&bb[lane*8];
  f32x4 b1 = *(const f32x4*)&bb[lane*8+4];
  float o[8];
  #pragma unroll
  for (int j=0;j<4;j++){
    o[j]   = (v[j]-mean)*inv*g0[j] + b0[j];
    o[4+j] = (v[4+j]-mean)*inv*g1[j] + b1[j];
  }
  if (FINAL == 0){
    u32x4 pk;
    #pragma unroll
    for (int j=0;j<4;j++)
      pk[j] = (u32)f2bf(o[2*j]) | ((u32)f2bf(o[2*j+1])<<16);
    *(u32x4*)&outb[(size_t)row*D_ + lane*8] = pk;
  } else {
    int s = row>>7, b = row&(B_-1);
    float* op = outf + ((size_t)b*S_ + s)*D_ + lane*8;
    f32x4 r0, r1;
    #pragma unroll
    for (int j=0;j<4;j++){ r0[j]=o[j]; r1[j]=o[4+j]; }
    *(f32x4*)op = r0;
    *(f32x4*)(op+4) = r1;
  }
}

// ---------- 256x256-tile bf16 MFMA GEMM, 8 waves, 4-deep LDS ring ----------
// BK=32 (64 B rows -> fragment ds_reads conflict-free, no swizzle needed).
// 4 x 32 KB ring: stage K-tile kt+2 while computing kt (buffer last read 2
// iterations / >=4 barriers ago -> race-free). Counted s_waitcnt vmcnt(4) at
// each K-tile boundary (never 0 mid-loop, T4); raw s_barrier (NOT
// __syncthreads: that drains vmcnt and kills the pipeline); setprio around
// the 16-MFMA clusters (T5). Per-wave output 128x64 = acc[8][4] (0.375 LDS
// reads/MFMA vs 0.5 in the old 128^2 kernel).
// MODE 0: QKV fused N=1536; MODE 1: residual += ; MODE 2: gelu->bf16
template<int MODE>
__global__ __launch_bounds__(512, 2) void gemm256(const u16* __restrict__ A,
    const u16* __restrict__ Wt, const float* __restrict__ bias,
    float* __restrict__ hres, u16* __restrict__ outb, int N, int K){
  const u32 nwg = gridDim.x * gridDim.y;
  u32 wg = blockIdx.y * gridDim.x + blockIdx.x;
  wg = (wg & 7) * (nwg >> 3) + (wg >> 3);   // bijective XCD chunk swizzle (nwg%8==0)
  const int m0 = (int)(wg / gridDim.x) * 256;
  const int n0 = (int)(wg % gridDim.x) * 256;
  __shared__ u16 lds[4][2][256*32];         // [ring buf][A,B][256 rows x 32 cols]
  const int t = threadIdx.x;
  const int lane = t & 63, wave = t >> 6;
  const int wm = wave >> 2, wn = wave & 3;  // 2 M-waves x 4 N-waves
  const int rsel = lane & 15, kb = (lane>>4)*8;
  const u16* ag = A  + (size_t)(m0 + (t>>2))*K + (t&3)*8;
  const u16* bg = Wt + (size_t)(n0 + (t>>2))*K + (t&3)*8;
  const int NT = K >> 5;
  auto stageA = [&](int kt){
    u16* dst = &lds[kt & 3][0][t*8];
    gload16(ag + kt*32,                  dst);
    gload16(ag + 128*(size_t)K + kt*32,  dst + 4096);
  };
  auto stageB = [&](int kt){
    u16* dst = &lds[kt & 3][1][t*8];
    gload16(bg + kt*32,                  dst);
    gload16(bg + 128*(size_t)K + kt*32,  dst + 4096);
  };
  f32x4 acc[8][4] = {};
  stageA(0); stageB(0); stageA(1); stageB(1);
  asm volatile("s_waitcnt vmcnt(4)" ::: "memory");   // K-tile 0 resident, 1 in flight
  __builtin_amdgcn_s_barrier();
  for (int kt = 0; kt < NT; ++kt){
    const u16* abuf = &lds[kt & 3][0][0];
    const u16* bbuf = &lds[kt & 3][1][0];
    // ---- phase A: frags A(m0-3) + B(n0-3); stage A(kt+2) ----
    u32x4 af[4], bf[4];
    #pragma unroll
    for (int i=0;i<4;i++) af[i] = *(const u32x4*)&abuf[(wm*128 + i*16 + rsel)*32 + kb];
    #pragma unroll
    for (int j=0;j<4;j++) bf[j] = *(const u32x4*)&bbuf[(wn*64 + j*16 + rsel)*32 + kb];
    if (kt + 2 < NT) stageA(kt+2);
    __builtin_amdgcn_s_barrier();
    __builtin_amdgcn_s_setprio(1);
    #pragma unroll
    for (int i=0;i<4;i++)
      #pragma unroll
      for (int j=0;j<4;j++)
        mfma16(acc[i][j], af[i], bf[j]);
    __builtin_amdgcn_s_setprio(0);
    __builtin_amdgcn_s_barrier();
    // ---- phase B: frags A(m4-7); stage B(kt+2) ----
    u32x4 af2[4];
    #pragma unroll
    for (int i=0;i<4;i++) af2[i] = *(const u32x4*)&abuf[(wm*128 + 64 + i*16 + rsel)*32 + kb];
    if (kt + 2 < NT) stageB(kt+2);
    __builtin_amdgcn_s_barrier();
    __builtin_amdgcn_s_setprio(1);
    #pragma unroll
    for (int i=0;i<4;i++)
      #pragma unroll
      for (int j=0;j<4;j++)
        mfma16(acc[4+i][j], af2[i], bf[j]);
    __builtin_amdgcn_s_setprio(0);
    // boundary: kt+1 must be resident (its 4 loads issued last iteration)
    if (kt < NT-2) asm volatile("s_waitcnt vmcnt(4)" ::: "memory");
    else           asm volatile("s_waitcnt vmcnt(0)" ::: "memory");
    __builtin_amdgcn_s_barrier();
  }
  asm volatile("s_nop 7\n\ts_nop 7");
  const int rb = (lane>>4)*4;
  #pragma unroll
  for (int i=0;i<8;i++){
    #pragma unroll
    for (int j=0;j<4;j++){
      int gn = n0 + wn*64 + j*16 + rsel;
      #pragma unroll
      for (int rg=0;rg<4;rg++){
        int gr = m0 + wm*128 + i*16 + rb + rg;
        float val = acc[i][j][rg];
        if (MODE == 0){
          int mat = gn >> 9;
          int hh = (gn >> 6) & 7, dd = gn & 63;
          int s = gr >> 7, b = gr & 127;
          u16* dst = outb + (size_t)mat*33554432ull;
          dst[(size_t)((s*H_ + hh)*B_ + b)*DK_ + dd] = f2bf(val);
        } else if (MODE == 1){
          hres[(size_t)gr*D_ + gn] += val + bias[gn];
        } else {
          float xg = val + bias[gn];
          float ge = 0.5f*xg*(1.f + erff(xg*0.7071067811865476f));
          outb[(size_t)gr*(size_t)N + gn] = f2bf(ge);
        }
      }
    }
  }
}

// ---------------- fused batch-attention per (s, head) ----------------
// MFMA PV; all register arrays statically indexed (rule #20).
__global__ __launch_bounds__(256, 2) void attn_kernel(const u16* __restrict__ qb,
    const u16* __restrict__ kb, const u16* __restrict__ vb, u16* __restrict__ cb){
  __shared__ __align__(16) char smem[80384];
  u16* q_lds = (u16*)smem;                 // [128][72]
  u16* k_lds = (u16*)(smem + 18432);       // [128][72]
  float* S   = (float*)smem;               // [128][132] f32, overlays q,k
  u16* P     = (u16*)smem;                 // [128][136] bf16, overlays dead S
  u16* vT    = (u16*)(smem + 34816);       // [64][136], overlays dead S
  u32* wl    = (u32*)(smem + 67584);       // [256][12] packed (bf16 w | idx)
  float* rs  = (float*)(smem + 79872);     // [128] inverse row sums
  int sh = blockIdx.x;
  int s = sh >> 3, hh = sh & 7;
  int t = threadIdx.x, lane = t & 63, wave = t >> 6;
  const u16* qg = qb + (size_t)sh * (B_*DK_);
  const u16* kg = kb + (size_t)sh * (B_*DK_);
  const u16* vg = vb + (size_t)sh * (B_*DK_);
  #pragma unroll
  for (int rr=0; rr<4; rr++){
    int idx = rr*2048 + t*8;
    int row = idx >> 6, col = idx & 63;
    *(u32x4*)&q_lds[row*72+col] = *(const u32x4*)&qg[idx];
    *(u32x4*)&k_lds[row*72+col] = *(const u32x4*)&kg[idx];
  }
  __syncthreads();
  int wm = wave>>1, wn = wave&1, rsel = lane & 15;
  f32x4 sacc[4][4] = {};
  #pragma unroll
  for (int ks=0; ks<2; ks++){
    asm volatile("s_nop 7\n\ts_nop 7");
    int ko = ks*32 + (lane>>4)*8;
    u32x4 qf[4], kf[4];
    #pragma unroll
    for (int i=0;i<4;i++){
      qf[i] = *(const u32x4*)&q_lds[(wm*64+i*16+rsel)*72 + ko];
      kf[i] = *(const u32x4*)&k_lds[(wn*64+i*16+rsel)*72 + ko];
    }
    #pragma unroll
    for (int i=0;i<4;i++)
      #pragma unroll
      for (int j=0;j<4;j++)
        mfma16(sacc[i][j], qf[i], kf[j]);
  }
  asm volatile("s_nop 7\n\ts_nop 7");
  __syncthreads();  // MFMA reads of q,k complete before S overlays them
  int rb = (lane>>4)*4;
  #pragma unroll
  for (int i=0;i<4;i++)
    #pragma unroll
    for (int j=0;j<4;j++)
      #pragma unroll
      for (int rg=0;rg<4;rg++)
        S[(wm*64+i*16+rb+rg)*132 + wn*64+j*16+rsel] = sacc[i][j][rg] * 0.125f;
  __syncthreads();
  // ---- per-row top-12 (2 threads/row, 64 elems each), vectorized reads ----
  int r = t >> 1, half = t & 1;
  const f32x4* srow4 = (const f32x4*)(S + r*132 + half*64);
  float kv[12];
  #pragma unroll
  for (int i=0;i<12;i++) kv[i] = -3.4e38f;
  for (int i4=0;i4<16;i4++){
    f32x4 v4 = srow4[i4];
    float m4 = fmaxf(fmaxf(v4[0],v4[1]), fmaxf(v4[2],v4[3]));
    if (m4 > kv[11]){
      #pragma unroll
      for (int z=0; z<4; z++){
        float inc = v4[z];
        if (inc > kv[11]){
          #pragma unroll
          for (int p=0;p<12;p++){
            float cur = kv[p];
            bool gt = inc > cur;
            kv[p] = gt ? inc : cur;
            inc   = gt ? cur : inc;
          }
        }
      }
    }
  }
  float kth = 3.4e38f;
  #pragma unroll
  for (int i=0;i<12;i++){
    float pb = __shfl_xor(kv[11-i], 1);
    kth = fminf(kth, fmaxf(kv[i], pb));
  }
  float mx = fmaxf(kv[0], __shfl_xor(kv[0], 1));
  // ---- exp + compact winners into wl ----
  float sum = 0.f;
  int n = 0;
  u32* myw = wl + t*12;
  for (int i4=0;i4<16;i4++){
    f32x4 v4 = srow4[i4];
    #pragma unroll
    for (int z=0; z<4; z++){
      float v = v4[z];
      if (v >= kth && n < 12){
        float e = __expf(v - mx);
        sum += e;
        myw[n] = ((u32)f2bf(e) << 16) | (u32)(half*64 + i4*4 + z);
        n++;
      }
    }
  }
  float tsum = sum + __shfl_xor(sum, 1);
  if (!half) rs[r] = 1.f / tsum;
  __syncthreads();           // S fully consumed by all threads
  // ---- zero P + stage V^T (both overlay dead S; disjoint regions) ----
  {
    u32x4 zz = {0u,0u,0u,0u};
    #pragma unroll
    for (int z=0; z<9; z++){
      int idx = z*256 + t;
      if (idx < 2176) ((u32x4*)P)[idx] = zz;
    }
  }
  #pragma unroll
  for (int rr=0; rr<16; rr++){
    int idx2 = (rr*256 + t)*2;
    u32 u = *(const u32*)&vg[idx2];
    int c = idx2 >> 6, d0 = idx2 & 63;
    vT[d0*136 + c]     = (u16)(u & 0xffffu);
    vT[(d0+1)*136 + c] = (u16)(u >> 16);
  }
  __syncthreads();
  // ---- scatter winners into P ----
  u16* prow = P + r*136;
  for (int j=0; j<n; j++){
    u32 e = myw[j];
    prow[e & 0xffffu] = (u16)(e >> 16);
  }
  __syncthreads();
  // ---- PV MFMA: ctx[128][64] = P[128][128] @ V[128][64] ----
  f32x4 cacc[4][2] = {};
  #pragma unroll
  for (int ks=0; ks<4; ks++){
    asm volatile("s_nop 7\n\ts_nop 7");
    int ko = ks*32 + (lane>>4)*8;
    u32x4 pf[4], vf[2];
    #pragma unroll
    for (int i=0;i<4;i++) pf[i] = *(const u32x4*)&P[(wm*64+i*16+rsel)*136 + ko];
    #pragma unroll
    for (int j=0;j<2;j++) vf[j] = *(const u32x4*)&vT[(wn*32+j*16+rsel)*136 + ko];
    #pragma unroll
    for (int i=0;i<4;i++)
      #pragma unroll
      for (int j=0;j<2;j++)
        mfma16(cacc[i][j], pf[i], vf[j]);
  }
  asm volatile("s_nop 7\n\ts_nop 7");
  #pragma unroll
  for (int i=0;i<4;i++)
    #pragma unroll
    for (int j=0;j<2;j++)
      #pragma unroll
      for (int rg=0;rg<4;rg++){
        int m = wm*64 + i*16 + rb + rg;
        int nn = wn*32 + j*16 + rsel;
        float val = cacc[i][j][rg] * rs[m];
        cb[((size_t)(s*B_ + m))*D_ + hh*DK_ + nn] = f2bf(val);
      }
}

extern "C" void kernel_launch(void* const* d_in, const int* in_sizes, int n_in,
                              void* d_out, int out_size, void* d_ws, size_t ws_size,
                              hipStream_t stream) {
  const float* x    = (const float*)d_in[0];
  const float* Win  = (const float*)d_in[1];
  const float* bin  = (const float*)d_in[2];
  const float* ln1g = (const float*)d_in[3];
  const float* ln1b = (const float*)d_in[4];
  const float* Wq   = (const float*)d_in[5];
  const float* Wk   = (const float*)d_in[6];
  const float* Wv   = (const float*)d_in[7];
  const float* Wo   = (const float*)d_in[8];
  const float* bo   = (const float*)d_in[9];
  const float* ln2g = (const float*)d_in[10];
  const float* ln2b = (const float*)d_in[11];
  const float* W1   = (const float*)d_in[12];
  const float* b1   = (const float*)d_in[13];
  const float* W2   = (const float*)d_in[14];
  const float* b2   = (const float*)d_in[15];
  const float* lnfg = (const float*)d_in[16];
  const float* lnfb = (const float*)d_in[17];

  char* ws = (char*)d_ws;
  float* h  = (float*)(ws);                      // 134217728 B
  u16* yb   = (u16*)(ws + 134217728ull);         // 67108864 B
  u16* qb   = (u16*)(ws + 201326592ull);         // q,k,v contiguous
  u16* kb   = (u16*)(ws + 268435456ull);
  u16* vb   = (u16*)(ws + 335544320ull);
  u16* cb   = (u16*)(ws + 402653184ull);
  u16* act  = qb;                                // overlays qb..cb
  u16* wqkvT= (u16*)(ws + 469762048ull);         // [L][3][D][D] = 6 MB
  u16* woT  = (u16*)(ws + 476053504ull);         // [L][D][D] = 2 MB
  u16* w1T  = (u16*)(ws + 478150656ull);         // 8 MB
  u16* w2T  = (u16*)(ws + 486539264ull);         // 8 MB
  float* pe = (float*)(ws + 494927872ull);       // 1 MB

  dim3 tb(32,8);
  pe_kernel<<<S_, D_, 0, stream>>>(pe);
  transpose_bf16<<<dim3(D_/32, D_/32, L_), tb, 0, stream>>>(Wq, wqkvT,            D_, D_, (size_t)3*D_*D_);
  transpose_bf16<<<dim3(D_/32, D_/32, L_), tb, 0, stream>>>(Wk, wqkvT + D_*D_,    D_, D_, (size_t)3*D_*D_);
  transpose_bf16<<<dim3(D_/32, D_/32, L_), tb, 0, stream>>>(Wv, wqkvT + 2*D_*D_,  D_, D_, (size_t)3*D_*D_);
  transpose_bf16<<<dim3(D_/32, D_/32, L_), tb, 0, stream>>>(Wo, woT,              D_, D_, (size_t)D_*D_);
  transpose_bf16<<<dim3(F_/32, D_/32, L_), tb, 0, stream>>>(W1, w1T, D_, F_, (size_t)D_*F_);
  transpose_bf16<<<dim3(D_/32, F_/32, L_), tb, 0, stream>>>(W2, w2T, F_, D_, (size_t)F_*D_);
  inproj_kernel<<<512, 512, 0, stream>>>(x, Win, bin, pe, h);

  for (int l=0; l<L_; l++){
    ln_kernel<0><<<SB_/4, 256, 0, stream>>>(h, ln1g + l*D_, ln1b + l*D_, yb, nullptr);
    gemm256<0><<<dim3(6,256), 512, 0, stream>>>(yb, wqkvT + (size_t)l*3*D_*D_, nullptr, nullptr, qb, 1536, D_);
    attn_kernel<<<S_*H_, 256, 0, stream>>>(qb, kb, vb, cb);
    gemm256<1><<<dim3(2,256), 512, 0, stream>>>(cb, woT + (size_t)l*D_*D_, bo + l*D_, h, nullptr, D_, D_);
    ln_kernel<0><<<SB_/4, 256, 0, stream>>>(h, ln2g + l*D_, ln2b + l*D_, yb, nullptr);
    gemm256<2><<<dim3(8,256), 512, 0, stream>>>(yb, w1T + (size_t)l*D_*F_, b1 + l*F_, nullptr, act, F_, D_);
    gemm256<1><<<dim3(2,256), 512, 0, stream>>>(act, w2T + (size_t)l*F_*D_, b2 + l*D_, h, nullptr, D_, F_);
  }
  ln_kernel<1><<<SB_/4, 256, 0, stream>>>(h, lnfg, lnfb, nullptr, (float*)d_out);
}

// Round 8
// 3554.125 us; speedup vs baseline: 1.7086x; 1.0150x over previous
//
#include <hip/hip_runtime.h>
#include <math.h>

#define S_ 512
#define B_ 128
#define D_ 512
#define I_ 64
#define F_ 2048
#define H_ 8
#define DK_ 64
#define L_ 4
#define SB_ (S_*B_)

typedef unsigned short u16;
typedef unsigned int u32;
typedef __attribute__((ext_vector_type(4))) unsigned int u32x4;
typedef __attribute__((ext_vector_type(4))) float f32x4;

__device__ __forceinline__ u16 f2bf(float f){
  u32 x = __builtin_bit_cast(u32, f);
  x += 0x7fffu + ((x >> 16) & 1u);
  return (u16)(x >> 16);
}

__device__ __forceinline__ void mfma16(f32x4& c, const u32x4& a, const u32x4& b){
  asm volatile("v_mfma_f32_16x16x32_bf16 %0, %1, %2, %0" : "+v"(c) : "v"(a), "v"(b));
}

// async global->LDS, 16 B per lane (m97 pattern)
__device__ __forceinline__ void gload16(const u16* g, u16* l){
  __builtin_amdgcn_global_load_lds((const __attribute__((address_space(1))) unsigned int*)g,
                                   (__attribute__((address_space(3))) unsigned int*)l, 16, 0, 0);
}

// fast GELU (tanh form): |err| vs exact erf-GELU <= ~1e-3, below bf16 ulp of act.
__device__ __forceinline__ float gelu_fast(float x){
  float u = 0.7978845608028654f * fmaf(0.044715f*x*x, x, x);
  float ae = __expf(-2.f*fabsf(u));
  float th = (1.f - ae) / (1.f + ae);
  th = (u < 0.f) ? -th : th;
  return 0.5f * x * (1.f + th);
}

// ---------------- positional encoding table ----------------
__global__ void pe_kernel(float* __restrict__ pe){
  int s = blockIdx.x, d = threadIdx.x;
  float e = expf((float)(d & ~1) * (-9.210340371976184f / (float)D_));
  float arg = (float)s * e;
  pe[s*D_ + d] = (d & 1) ? cosf(arg) : sinf(arg);
}

// ---------------- weight transpose + fp32->bf16 ----------------
__global__ void transpose_bf16(const float* __restrict__ src, u16* __restrict__ dst,
                               int R, int C, size_t zstride){
  __shared__ float t[32][33];
  size_t sbase = (size_t)blockIdx.z * R * C;
  size_t dbase = (size_t)blockIdx.z * zstride;
  int r0 = blockIdx.y*32, c0 = blockIdx.x*32;
  int tx = threadIdx.x, ty = threadIdx.y;
  #pragma unroll
  for (int j=0;j<4;j++)
    t[ty+j*8][tx] = src[sbase + (size_t)(r0+ty+j*8)*C + c0+tx];
  __syncthreads();
  #pragma unroll
  for (int j=0;j<4;j++)
    dst[dbase + (size_t)(c0+ty+j*8)*R + r0+tx] = f2bf(t[tx][ty+j*8]);
}

// ---------------- input projection + scale + PE ----------------
__global__ __launch_bounds__(512) void inproj_kernel(const float* __restrict__ x,
    const float* __restrict__ Win, const float* __restrict__ bin,
    const float* __restrict__ pe, float* __restrict__ h){
  __shared__ float xs[8][64];
  int t = threadIdx.x;           // = output column d
  float w[64];
  #pragma unroll
  for (int i=0;i<64;i++) w[i] = Win[i*D_ + t];
  float bd = bin[t];
  int r0 = blockIdx.x * 128;
  for (int batch=0; batch<16; batch++){
    int rb = r0 + batch*8;
    {
      int rr = t >> 6, i = t & 63;
      int r = rb + rr;
      int s = r >> 7, b = r & 127;
      xs[rr][i] = x[((size_t)b*S_ + s)*I_ + i];
    }
    __syncthreads();
    float acc[8];
    #pragma unroll
    for (int rr=0;rr<8;rr++) acc[rr] = 0.f;
    #pragma unroll
    for (int i4=0;i4<16;i4++){
      f32x4 xv[8];
      #pragma unroll
      for (int rr=0;rr<8;rr++) xv[rr] = *(const f32x4*)&xs[rr][i4*4];
      #pragma unroll
      for (int rr=0;rr<8;rr++){
        acc[rr] = fmaf(xv[rr][0], w[i4*4+0], acc[rr]);
        acc[rr] = fmaf(xv[rr][1], w[i4*4+1], acc[rr]);
        acc[rr] = fmaf(xv[rr][2], w[i4*4+2], acc[rr]);
        acc[rr] = fmaf(xv[rr][3], w[i4*4+3], acc[rr]);
      }
    }
    #pragma unroll
    for (int rr=0;rr<8;rr++){
      int r = rb + rr;
      int s = r >> 7;
      h[(size_t)r*D_ + t] = (acc[rr] + bd) * 22.627416997969522f + pe[s*D_ + t];
    }
    __syncthreads();
  }
}

// ---------------- LayerNorm ----------------
template<int FINAL>
__global__ __launch_bounds__(256) void ln_kernel(const float* __restrict__ hsrc,
    const float* __restrict__ g, const float* __restrict__ bb,
    u16* __restrict__ outb, float* __restrict__ outf){
  int row = blockIdx.x*4 + (threadIdx.x>>6);
  int lane = threadIdx.x & 63;
  const float* hr = hsrc + (size_t)row*D_ + lane*8;
  f32x4 a0 = *(const f32x4*)hr;
  f32x4 a1 = *(const f32x4*)(hr+4);
  float v[8];
  #pragma unroll
  for (int j=0;j<4;j++){ v[j]=a0[j]; v[4+j]=a1[j]; }
  float sum = 0.f;
  #pragma unroll
  for (int j=0;j<8;j++) sum += v[j];
  #pragma unroll
  for (int m=1;m<64;m<<=1) sum += __shfl_xor(sum, m);
  float mean = sum * (1.f/(float)D_);
  float s2 = 0.f;
  #pragma unroll
  for (int j=0;j<8;j++){ float dd = v[j]-mean; s2 = fmaf(dd,dd,s2); }
  #pragma unroll
  for (int m=1;m<64;m<<=1) s2 += __shfl_xor(s2, m);
  float inv = rsqrtf(s2*(1.f/(float)D_) + 1e-5f);
  f32x4 g0 = *(const f32x4*)&g[lane*8];
  f32x4 g1 = *(const f32x4*)&g[lane*8+4];
  f32x4 b0 = *(const f32x4*)&bb[lane*8];
  f32x4 b1 = *(const f32x4*)&bb[lane*8+4];
  float o[8];
  #pragma unroll
  for (int j=0;j<4;j++){
    o[j]   = (v[j]-mean)*inv*g0[j] + b0[j];
    o[4+j] = (v[4+j]-mean)*inv*g1[j] + b1[j];
  }
  if (FINAL == 0){
    u32x4 pk;
    #pragma unroll
    for (int j=0;j<4;j++)
      pk[j] = (u32)f2bf(o[2*j]) | ((u32)f2bf(o[2*j+1])<<16);
    *(u32x4*)&outb[(size_t)row*D_ + lane*8] = pk;
  } else {
    int s = row>>7, b = row&(B_-1);
    float* op = outf + ((size_t)b*S_ + s)*D_ + lane*8;
    f32x4 r0, r1;
    #pragma unroll
    for (int j=0;j<4;j++){ r0[j]=o[j]; r1[j]=o[4+j]; }
    *(f32x4*)op = r0;
    *(f32x4*)(op+4) = r1;
  }
}

// ---------- 256x256-tile bf16 MFMA GEMM, 8 waves, 4-deep LDS ring ----------
// r7->r8: T2 slot-XOR swizzle (rule #21 both-sides): logical k-slot s of row r
// stored at physical slot s^((r>>1)&3). Stage keeps LDS dest LINEAR and
// pre-swizzles the GLOBAL source slot ((t&3)^((t>>3)&3)); reads XOR the slot.
// 16-lane fragment groups then cover all 8 four-bank spans exactly twice
// (2-way = free) instead of the 8-way 64-B-row conflict (was 1.26e7/dispatch).
// Counted vmcnt(4) at K-tile boundary (T4), raw s_barrier, setprio (T5).
template<int MODE>
__global__ __launch_bounds__(512, 2) void gemm256(const u16* __restrict__ A,
    const u16* __restrict__ Wt, const float* __restrict__ bias,
    float* __restrict__ hres, u16* __restrict__ outb, int N, int K){
  const u32 nwg = gridDim.x * gridDim.y;
  u32 wg = blockIdx.y * gridDim.x + blockIdx.x;
  wg = (wg & 7) * (nwg >> 3) + (wg >> 3);   // bijective XCD chunk swizzle (nwg%8==0)
  const int m0 = (int)(wg / gridDim.x) * 256;
  const int n0 = (int)(wg % gridDim.x) * 256;
  __shared__ u16 lds[4][2][256*32];         // [ring buf][A,B][256 rows x 32 cols]
  const int t = threadIdx.x;
  const int lane = t & 63, wave = t >> 6;
  const int wm = wave >> 2, wn = wave & 3;  // 2 M-waves x 4 N-waves
  const int rsel = lane & 15;
  // swizzled read offset: physical slot = kg ^ ((rsel>>1)&3)  (row bases %16==0)
  const int kswz = (((lane>>4) ^ ((rsel>>1)&3)) * 8);
  // swizzled stage source: thread t fills physical chunk t -> logical slot (t&3)^((t>>3)&3)
  const int sslot = (t&3) ^ ((t>>3)&3);
  const u16* ag = A  + (size_t)(m0 + (t>>2))*K + sslot*8;
  const u16* bg = Wt + (size_t)(n0 + (t>>2))*K + sslot*8;
  const int NT = K >> 5;
  auto stageA = [&](int kt){
    u16* dst = &lds[kt & 3][0][t*8];
    gload16(ag + kt*32,                  dst);
    gload16(ag + 128*(size_t)K + kt*32,  dst + 4096);
  };
  auto stageB = [&](int kt){
    u16* dst = &lds[kt & 3][1][t*8];
    gload16(bg + kt*32,                  dst);
    gload16(bg + 128*(size_t)K + kt*32,  dst + 4096);
  };
  f32x4 acc[8][4] = {};
  stageA(0); stageB(0); stageA(1); stageB(1);
  asm volatile("s_waitcnt vmcnt(4)" ::: "memory");   // K-tile 0 resident, 1 in flight
  __builtin_amdgcn_s_barrier();
  for (int kt = 0; kt < NT; ++kt){
    const u16* abuf = &lds[kt & 3][0][0];
    const u16* bbuf = &lds[kt & 3][1][0];
    // ---- phase A: frags A(m0-3) + B(n0-3); stage A(kt+2) ----
    u32x4 af[4], bf[4];
    #pragma unroll
    for (int i=0;i<4;i++) af[i] = *(const u32x4*)&abuf[(wm*128 + i*16 + rsel)*32 + kswz];
    #pragma unroll
    for (int j=0;j<4;j++) bf[j] = *(const u32x4*)&bbuf[(wn*64 + j*16 + rsel)*32 + kswz];
    if (kt + 2 < NT) stageA(kt+2);
    __builtin_amdgcn_s_barrier();
    __builtin_amdgcn_s_setprio(1);
    #pragma unroll
    for (int i=0;i<4;i++)
      #pragma unroll
      for (int j=0;j<4;j++)
        mfma16(acc[i][j], af[i], bf[j]);
    __builtin_amdgcn_s_setprio(0);
    __builtin_amdgcn_s_barrier();
    // ---- phase B: frags A(m4-7); stage B(kt+2) ----
    u32x4 af2[4];
    #pragma unroll
    for (int i=0;i<4;i++) af2[i] = *(const u32x4*)&abuf[(wm*128 + 64 + i*16 + rsel)*32 + kswz];
    if (kt + 2 < NT) stageB(kt+2);
    __builtin_amdgcn_s_barrier();
    __builtin_amdgcn_s_setprio(1);
    #pragma unroll
    for (int i=0;i<4;i++)
      #pragma unroll
      for (int j=0;j<4;j++)
        mfma16(acc[4+i][j], af2[i], bf[j]);
    __builtin_amdgcn_s_setprio(0);
    // boundary: kt+1 must be resident (its 4 loads issued last iteration)
    if (kt < NT-2) asm volatile("s_waitcnt vmcnt(4)" ::: "memory");
    else           asm volatile("s_waitcnt vmcnt(0)" ::: "memory");
    __builtin_amdgcn_s_barrier();
  }
  asm volatile("s_nop 7\n\ts_nop 7");
  const int rb = (lane>>4)*4;
  #pragma unroll
  for (int i=0;i<8;i++){
    #pragma unroll
    for (int j=0;j<4;j++){
      int gn = n0 + wn*64 + j*16 + rsel;
      #pragma unroll
      for (int rg=0;rg<4;rg++){
        int gr = m0 + wm*128 + i*16 + rb + rg;
        float val = acc[i][j][rg];
        if (MODE == 0){
          int mat = gn >> 9;
          int hh = (gn >> 6) & 7, dd = gn & 63;
          int s = gr >> 7, b = gr & 127;
          u16* dst = outb + (size_t)mat*33554432ull;
          dst[(size_t)((s*H_ + hh)*B_ + b)*DK_ + dd] = f2bf(val);
        } else if (MODE == 1){
          hres[(size_t)gr*D_ + gn] += val + bias[gn];
        } else {
          outb[(size_t)gr*(size_t)N + gn] = f2bf(gelu_fast(val + bias[gn]));
        }
      }
    }
  }
}

// ---------------- fused batch-attention per (s, head) ----------------
// MFMA PV; all register arrays statically indexed (rule #20).
__global__ __launch_bounds__(256, 2) void attn_kernel(const u16* __restrict__ qb,
    const u16* __restrict__ kb, const u16* __restrict__ vb, u16* __restrict__ cb){
  __shared__ __align__(16) char smem[80384];
  u16* q_lds = (u16*)smem;                 // [128][72]
  u16* k_lds = (u16*)(smem + 18432);       // [128][72]
  float* S   = (float*)smem;               // [128][132] f32, overlays q,k
  u16* P     = (u16*)smem;                 // [128][136] bf16, overlays dead S
  u16* vT    = (u16*)(smem + 34816);       // [64][136], overlays dead S
  u32* wl    = (u32*)(smem + 67584);       // [256][12] packed (bf16 w | idx)
  float* rs  = (float*)(smem + 79872);     // [128] inverse row sums
  int sh = blockIdx.x;
  int s = sh >> 3, hh = sh & 7;
  int t = threadIdx.x, lane = t & 63, wave = t >> 6;
  const u16* qg = qb + (size_t)sh * (B_*DK_);
  const u16* kg = kb + (size_t)sh * (B_*DK_);
  const u16* vg = vb + (size_t)sh * (B_*DK_);
  #pragma unroll
  for (int rr=0; rr<4; rr++){
    int idx = rr*2048 + t*8;
    int row = idx >> 6, col = idx & 63;
    *(u32x4*)&q_lds[row*72+col] = *(const u32x4*)&qg[idx];
    *(u32x4*)&k_lds[row*72+col] = *(const u32x4*)&kg[idx];
  }
  __syncthreads();
  int wm = wave>>1, wn = wave&1, rsel = lane & 15;
  f32x4 sacc[4][4] = {};
  #pragma unroll
  for (int ks=0; ks<2; ks++){
    asm volatile("s_nop 7\n\ts_nop 7");
    int ko = ks*32 + (lane>>4)*8;
    u32x4 qf[4], kf[4];
    #pragma unroll
    for (int i=0;i<4;i++){
      qf[i] = *(const u32x4*)&q_lds[(wm*64+i*16+rsel)*72 + ko];
      kf[i] = *(const u32x4*)&k_lds[(wn*64+i*16+rsel)*72 + ko];
    }
    #pragma unroll
    for (int i=0;i<4;i++)
      #pragma unroll
      for (int j=0;j<4;j++)
        mfma16(sacc[i][j], qf[i], kf[j]);
  }
  asm volatile("s_nop 7\n\ts_nop 7");
  __syncthreads();  // MFMA reads of q,k complete before S overlays them
  int rb = (lane>>4)*4;
  #pragma unroll
  for (int i=0;i<4;i++)
    #pragma unroll
    for (int j=0;j<4;j++)
      #pragma unroll
      for (int rg=0;rg<4;rg++)
        S[(wm*64+i*16+rb+rg)*132 + wn*64+j*16+rsel] = sacc[i][j][rg] * 0.125f;
  __syncthreads();
  // ---- per-row top-12 (2 threads/row, 64 elems each), vectorized reads ----
  int r = t >> 1, half = t & 1;
  const f32x4* srow4 = (const f32x4*)(S + r*132 + half*64);
  float kv[12];
  #pragma unroll
  for (int i=0;i<12;i++) kv[i] = -3.4e38f;
  for (int i4=0;i4<16;i4++){
    f32x4 v4 = srow4[i4];
    float m4 = fmaxf(fmaxf(v4[0],v4[1]), fmaxf(v4[2],v4[3]));
    if (m4 > kv[11]){
      #pragma unroll
      for (int z=0; z<4; z++){
        float inc = v4[z];
        if (inc > kv[11]){
          #pragma unroll
          for (int p=0;p<12;p++){
            float cur = kv[p];
            bool gt = inc > cur;
            kv[p] = gt ? inc : cur;
            inc   = gt ? cur : inc;
          }
        }
      }
    }
  }
  float kth = 3.4e38f;
  #pragma unroll
  for (int i=0;i<12;i++){
    float pb = __shfl_xor(kv[11-i], 1);
    kth = fminf(kth, fmaxf(kv[i], pb));
  }
  float mx = fmaxf(kv[0], __shfl_xor(kv[0], 1));
  // ---- exp + compact winners into wl ----
  float sum = 0.f;
  int n = 0;
  u32* myw = wl + t*12;
  for (int i4=0;i4<16;i4++){
    f32x4 v4 = srow4[i4];
    #pragma unroll
    for (int z=0; z<4; z++){
      float v = v4[z];
      if (v >= kth && n < 12){
        float e = __expf(v - mx);
        sum += e;
        myw[n] = ((u32)f2bf(e) << 16) | (u32)(half*64 + i4*4 + z);
        n++;
      }
    }
  }
  float tsum = sum + __shfl_xor(sum, 1);
  if (!half) rs[r] = 1.f / tsum;
  __syncthreads();           // S fully consumed by all threads
  // ---- zero P + stage V^T (both overlay dead S; disjoint regions) ----
  {
    u32x4 zz = {0u,0u,0u,0u};
    #pragma unroll
    for (int z=0; z<9; z++){
      int idx = z*256 + t;
      if (idx < 2176) ((u32x4*)P)[idx] = zz;
    }
  }
  #pragma unroll
  for (int rr=0; rr<16; rr++){
    int idx2 = (rr*256 + t)*2;
    u32 u = *(const u32*)&vg[idx2];
    int c = idx2 >> 6, d0 = idx2 & 63;
    vT[d0*136 + c]     = (u16)(u & 0xffffu);
    vT[(d0+1)*136 + c] = (u16)(u >> 16);
  }
  __syncthreads();
  // ---- scatter winners into P ----
  u16* prow = P + r*136;
  for (int j=0; j<n; j++){
    u32 e = myw[j];
    prow[e & 0xffffu] = (u16)(e >> 16);
  }
  __syncthreads();
  // ---- PV MFMA: ctx[128][64] = P[128][128] @ V[128][64] ----
  f32x4 cacc[4][2] = {};
  #pragma unroll
  for (int ks=0; ks<4; ks++){
    asm volatile("s_nop 7\n\ts_nop 7");
    int ko = ks*32 + (lane>>4)*8;
    u32x4 pf[4], vf[2];
    #pragma unroll
    for (int i=0;i<4;i++) pf[i] = *(const u32x4*)&P[(wm*64+i*16+rsel)*136 + ko];
    #pragma unroll
    for (int j=0;j<2;j++) vf[j] = *(const u32x4*)&vT[(wn*32+j*16+rsel)*136 + ko];
    #pragma unroll
    for (int i=0;i<4;i++)
      #pragma unroll
      for (int j=0;j<2;j++)
        mfma16(cacc[i][j], pf[i], vf[j]);
  }
  asm volatile("s_nop 7\n\ts_nop 7");
  #pragma unroll
  for (int i=0;i<4;i++)
    #pragma unroll
    for (int j=0;j<2;j++)
      #pragma unroll
      for (int rg=0;rg<4;rg++){
        int m = wm*64 + i*16 + rb + rg;
        int nn = wn*32 + j*16 + rsel;
        float val = cacc[i][j][rg] * rs[m];
        cb[((size_t)(s*B_ + m))*D_ + hh*DK_ + nn] = f2bf(val);
      }
}

extern "C" void kernel_launch(void* const* d_in, const int* in_sizes, int n_in,
                              void* d_out, int out_size, void* d_ws, size_t ws_size,
                              hipStream_t stream) {
  const float* x    = (const float*)d_in[0];
  const float* Win  = (const float*)d_in[1];
  const float* bin  = (const float*)d_in[2];
  const float* ln1g = (const float*)d_in[3];
  const float* ln1b = (const float*)d_in[4];
  const float* Wq   = (const float*)d_in[5];
  const float* Wk   = (const float*)d_in[6];
  const float* Wv   = (const float*)d_in[7];
  const float* Wo   = (const float*)d_in[8];
  const float* bo   = (const float*)d_in[9];
  const float* ln2g = (const float*)d_in[10];
  const float* ln2b = (const float*)d_in[11];
  const float* W1   = (const float*)d_in[12];
  const float* b1   = (const float*)d_in[13];
  const float* W2   = (const float*)d_in[14];
  const float* b2   = (const float*)d_in[15];
  const float* lnfg = (const float*)d_in[16];
  const float* lnfb = (const float*)d_in[17];

  char* ws = (char*)d_ws;
  float* h  = (float*)(ws);                      // 134217728 B
  u16* yb   = (u16*)(ws + 134217728ull);         // 67108864 B
  u16* qb   = (u16*)(ws + 201326592ull);         // q,k,v contiguous
  u16* kb   = (u16*)(ws + 268435456ull);
  u16* vb   = (u16*)(ws + 335544320ull);
  u16* cb   = (u16*)(ws + 402653184ull);
  u16* act  = qb;                                // overlays qb..cb
  u16* wqkvT= (u16*)(ws + 469762048ull);         // [L][3][D][D] = 6 MB
  u16* woT  = (u16*)(ws + 476053504ull);         // [L][D][D] = 2 MB
  u16* w1T  = (u16*)(ws + 478150656ull);         // 8 MB
  u16* w2T  = (u16*)(ws + 486539264ull);         // 8 MB
  float* pe = (float*)(ws + 494927872ull);       // 1 MB

  dim3 tb(32,8);
  pe_kernel<<<S_, D_, 0, stream>>>(pe);
  transpose_bf16<<<dim3(D_/32, D_/32, L_), tb, 0, stream>>>(Wq, wqkvT,            D_, D_, (size_t)3*D_*D_);
  transpose_bf16<<<dim3(D_/32, D_/32, L_), tb, 0, stream>>>(Wk, wqkvT + D_*D_,    D_, D_, (size_t)3*D_*D_);
  transpose_bf16<<<dim3(D_/32, D_/32, L_), tb, 0, stream>>>(Wv, wqkvT + 2*D_*D_,  D_, D_, (size_t)3*D_*D_);
  transpose_bf16<<<dim3(D_/32, D_/32, L_), tb, 0, stream>>>(Wo, woT,              D_, D_, (size_t)D_*D_);
  transpose_bf16<<<dim3(F_/32, D_/32, L_), tb, 0, stream>>>(W1, w1T, D_, F_, (size_t)D_*F_);
  transpose_bf16<<<dim3(D_/32, F_/32, L_), tb, 0, stream>>>(W2, w2T, F_, D_, (size_t)F_*D_);
  inproj_kernel<<<512, 512, 0, stream>>>(x, Win, bin, pe, h);

  for (int l=0; l<L_; l++){
    ln_kernel<0><<<SB_/4, 256, 0, stream>>>(h, ln1g + l*D_, ln1b + l*D_, yb, nullptr);
    gemm256<0><<<dim3(6,256), 512, 0, stream>>>(yb, wqkvT + (size_t)l*3*D_*D_, nullptr, nullptr, qb, 1536, D_);
    attn_kernel<<<S_*H_, 256, 0, stream>>>(qb, kb, vb, cb);
    gemm256<1><<<dim3(2,256), 512, 0, stream>>>(cb, woT + (size_t)l*D_*D_, bo + l*D_, h, nullptr, D_, D_);
    ln_kernel<0><<<SB_/4, 256, 0, stream>>>(h, ln2g + l*D_, ln2b + l*D_, yb, nullptr);
    gemm256<2><<<dim3(8,256), 512, 0, stream>>>(yb, w1T + (size_t)l*D_*F_, b1 + l*F_, nullptr, act, F_, D_);
    gemm256<1><<<dim3(2,256), 512, 0, stream>>>(act, w2T + (size_t)l*F_*D_, b2 + l*D_, h, nullptr, D_, F_);
  }
  ln_kernel<1><<<SB_/4, 256, 0, stream>>>(h, lnfg, lnfb, nullptr, (float*)d_out);
}